// Round 5
// baseline (172.357 us; speedup 1.0000x reference)
//
#include <hip/hip_runtime.h>
#include <hip/hip_bf16.h>

typedef __bf16 bf16_t;
typedef bf16_t bf16x8 __attribute__((ext_vector_type(8)));
typedef bf16_t bf16x4 __attribute__((ext_vector_type(4)));
typedef float f32x4 __attribute__((ext_vector_type(4)));
typedef float f32x16 __attribute__((ext_vector_type(16)));

#define EXP2C 0.1803368867f  // 0.125 * log2(e)
#define FEXP2(x) __builtin_amdgcn_exp2f(x)  // v_exp_f32 (base-2)

// async global->LDS, 16B per lane (dest must be wave-uniform base + lane*16)
__device__ __forceinline__ void gload16(const void* g, void* l) {
  __builtin_amdgcn_global_load_lds(
      (const __attribute__((address_space(1))) void*)g,
      (__attribute__((address_space(3))) void*)l, 16, 0, 0);
}

__device__ __forceinline__ unsigned pkbf(float lo, float hi) {
  unsigned short a = __builtin_bit_cast(unsigned short, (bf16_t)lo);
  unsigned short b = __builtin_bit_cast(unsigned short, (bf16_t)hi);
  return (unsigned)a | ((unsigned)b << 16);
}

// ---------------------------------------------------------------------------
// convert f32 -> bf16, vectorized
// ---------------------------------------------------------------------------
__global__ __launch_bounds__(256) void cvt_kernel(const float* __restrict__ in,
                                                  bf16_t* __restrict__ out, int n4) {
  int i = blockIdx.x * 256 + threadIdx.x;
  if (i >= n4) return;
  float4 v = reinterpret_cast<const float4*>(in)[i];
  bf16x4 o = { (bf16_t)v.x, (bf16_t)v.y, (bf16_t)v.z, (bf16_t)v.w };
  reinterpret_cast<bf16x4*>(out)[i] = o;
}

// ---------------------------------------------------------------------------
// transpose + convert: W[K][N] f32 -> Wt[N][K] bf16
// ---------------------------------------------------------------------------
__global__ __launch_bounds__(256) void tcvt_kernel(const float* __restrict__ W,
                                                   bf16_t* __restrict__ Wt,
                                                   int K, int N) {
  __shared__ float tile[32][33];
  int tx = threadIdx.x & 31, ty = threadIdx.x >> 5;
  int n0 = blockIdx.x * 32, k0 = blockIdx.y * 32;
#pragma unroll
  for (int i = 0; i < 4; ++i)
    tile[ty + i * 8][tx] = W[(size_t)(k0 + ty + i * 8) * N + n0 + tx];
  __syncthreads();
#pragma unroll
  for (int i = 0; i < 4; ++i)
    Wt[(size_t)(n0 + ty + i * 8) * K + k0 + tx] = (bf16_t)tile[tx][ty + i * 8];
}

// ---------------------------------------------------------------------------
// V transpose per head: src[b*R + s][stride] cols (coloff + h*64 + d)
//   -> vT[(bh*64 + d)*R + s]
// ---------------------------------------------------------------------------
__global__ __launch_bounds__(256) void vtrans_kernel(const bf16_t* __restrict__ src,
                                                     bf16_t* __restrict__ vT,
                                                     int R, int stride, int coloff) {
  __shared__ bf16_t tile[64][72];
  const int tid = threadIdx.x;
  const int bh = blockIdx.y, s0 = blockIdx.x * 64;
  const int b = bh >> 4, h = bh & 15;
#pragma unroll
  for (int it = 0; it < 2; ++it) {
    int idx = it * 256 + tid;
    int r = idx >> 3, c8 = idx & 7;
    *(bf16x8*)&tile[r][c8 * 8] =
        *(const bf16x8*)&src[(size_t)(b * R + s0 + r) * stride + coloff + h * 64 + c8 * 8];
  }
  __syncthreads();
#pragma unroll
  for (int it = 0; it < 2; ++it) {
    int idx = it * 256 + tid;
    int d = idx >> 3, ch = idx & 7;
    bf16x8 o;
#pragma unroll
    for (int j = 0; j < 8; ++j) o[j] = tile[ch * 8 + j][d];
    *(bf16x8*)&vT[(size_t)(bh * 64 + d) * R + s0 + ch * 8] = o;
  }
}

// ---------------------------------------------------------------------------
// GEMM: C[M][N] = A[M][K] @ Bt[N][K]^T + bias.  128x128 tile, BK=32,
// 4 waves, 4x4 mfma_f32_16x16x32_bf16. 2-phase double-buffered
// global_load_lds staging.
// ---------------------------------------------------------------------------
template <int OUTF32>
__global__ __launch_bounds__(256) void gemm_bt_kernel(
    const bf16_t* __restrict__ A, const bf16_t* __restrict__ Bt,
    const float* __restrict__ bias, void* __restrict__ Cout,
    int M, int N, int K) {
  __shared__ __align__(16) bf16_t sA[2][128 * 32];
  __shared__ __align__(16) bf16_t sB[2][128 * 32];
  const int tid = threadIdx.x;
  const int l = tid & 63, w = tid >> 6;
  const int lr = l & 15, lg = l >> 4;
  const int m0 = blockIdx.y * 128, n0 = blockIdx.x * 128;
  const int wr = (w >> 1) * 64, wc = (w & 1) * 64;

  const int i0 = tid, i1 = tid + 256;
  const bf16_t* ga0 = A + (size_t)(m0 + (i0 >> 2)) * K + (i0 & 3) * 8;
  const bf16_t* ga1 = A + (size_t)(m0 + (i1 >> 2)) * K + (i1 & 3) * 8;
  const bf16_t* gb0 = Bt + (size_t)(n0 + (i0 >> 2)) * K + (i0 & 3) * 8;
  const bf16_t* gb1 = Bt + (size_t)(n0 + (i1 >> 2)) * K + (i1 & 3) * 8;

  f32x4 acc[4][4] = {};

  const int nk = K >> 5;
  gload16(ga0, &sA[0][i0 * 8]);
  gload16(ga1, &sA[0][i1 * 8]);
  gload16(gb0, &sB[0][i0 * 8]);
  gload16(gb1, &sB[0][i1 * 8]);
  __syncthreads();

  int cur = 0;
  for (int kt = 0; kt < nk; ++kt) {
    if (kt + 1 < nk) {
      const int ko = (kt + 1) * 32;
      gload16(ga0 + ko, &sA[cur ^ 1][i0 * 8]);
      gload16(ga1 + ko, &sA[cur ^ 1][i1 * 8]);
      gload16(gb0 + ko, &sB[cur ^ 1][i0 * 8]);
      gload16(gb1 + ko, &sB[cur ^ 1][i1 * 8]);
    }
    bf16x8 af[4], bv[4];
#pragma unroll
    for (int mf = 0; mf < 4; ++mf)
      af[mf] = *(const bf16x8*)&sA[cur][(wr + mf * 16 + lr) * 32 + lg * 8];
#pragma unroll
    for (int nf = 0; nf < 4; ++nf)
      bv[nf] = *(const bf16x8*)&sB[cur][(wc + nf * 16 + lr) * 32 + lg * 8];
#pragma unroll
    for (int mf = 0; mf < 4; ++mf)
#pragma unroll
      for (int nf = 0; nf < 4; ++nf)
        acc[mf][nf] = __builtin_amdgcn_mfma_f32_16x16x32_bf16(af[mf], bv[nf], acc[mf][nf], 0, 0, 0);
    __syncthreads();
    cur ^= 1;
  }

#pragma unroll
  for (int mf = 0; mf < 4; ++mf) {
#pragma unroll
    for (int nf = 0; nf < 4; ++nf) {
      int col = n0 + wc + nf * 16 + lr;
      float bb = bias[col];
      int rowb = m0 + wr + mf * 16 + lg * 4;
#pragma unroll
      for (int r = 0; r < 4; ++r) {
        float v = acc[mf][nf][r] + bb;
        if constexpr (OUTF32)
          ((float*)Cout)[(size_t)(rowb + r) * N + col] = v;
        else
          ((bf16_t*)Cout)[(size_t)(rowb + r) * N + col] = (bf16_t)v;
      }
    }
  }
}

// ---------------------------------------------------------------------------
// Unified flash attention with intra-block split-KV.
// One BLOCK = one (bh, q-tile); its 4 waves process interleaved kv-tiles
// (t = w, w+4, ...), each keeping private (m, l, O^T). Epilogue merges the
// 4 partials in LDS: O = sum_w O_w * exp2((m_w - M)*c), L likewise — exact.
// Swapped QK^T (mfma(K,Q)): lane owns q-row = lane&31. KVBLK=32.
// K prefetched one tile ahead. Raw-domain softmax. P stays in registers.
// ---------------------------------------------------------------------------
__global__ __launch_bounds__(256, 2) void attn_kernel(
    const bf16_t* __restrict__ qkv,   // [4096][3072]
    const bf16_t* __restrict__ kkv,   // [1024][2048]
    const bf16_t* __restrict__ vTs,   // [64][64][1024]  self V^T
    const bf16_t* __restrict__ vTc,   // [64][64][256]   cross V^T
    bf16_t* __restrict__ obuf) {      // [8192][1024]
  __shared__ float sO[4][34][66];           // [wave][j: 32 acc + m + l][lane]
  __shared__ __align__(16) char swb[4096];  // wave-0 output staging

  const int tid = threadIdx.x;
  const int w = tid >> 6, l = tid & 63;
  const int ql = l & 31;
  const bool uhi = l >= 32;
  const int hi8 = uhi ? 8 : 0;
  const int kv4 = uhi ? 4 : 0;

  const int bid = blockIdx.x;
  const bool is_self = bid < 2048;
  int qt, bh, nt;
  if (is_self) {  // heaviest q-tiles (qt=31) dispatch first
    qt = 31 - (bid >> 6);
    bh = bid & 63;
    nt = qt + 1;
  } else {
    int cb = bid - 2048;
    qt = cb >> 6;
    bh = cb & 63;
    nt = 8;
  }
  const int b = bh >> 4, h = bh & 15;
  const int hcol = h * 64;
  const int q0 = qt * 32;

  const bf16_t* ksrc;
  const bf16_t* vsrc;
  int kstride, kvb, vlen, ooff;
  if (is_self) {
    ksrc = qkv + 1024 + hcol; kstride = 3072; kvb = b * 1024;
    vsrc = vTs + (size_t)bh * 64 * 1024; vlen = 1024; ooff = 0;
  } else {
    ksrc = kkv + hcol; kstride = 2048; kvb = b * 256;
    vsrc = vTc + (size_t)bh * 64 * 256; vlen = 256; ooff = 1024;
  }

  // Q fragments (B-operand): lane holds col q = ql, k = hd = ks*16 + hi8 + j
  const bf16_t* qrow = qkv + (size_t)(b * 1024 + q0 + ql) * 3072 + hcol + hi8;
  bf16x8 qf[4];
#pragma unroll
  for (int ks = 0; ks < 4; ++ks) qf[ks] = *(const bf16x8*)(qrow + ks * 16);

  float mcur = -1e30f, lcur = 0.f;  // mcur in RAW (pre-scale) units
  f32x16 oacc[2] = {};

  // prefetch K for this wave's first tile (t = w)
  bf16x8 kf[4], nkf[4];
  if (w < nt) {
    const bf16_t* kr = ksrc + (size_t)(kvb + w * 32 + ql) * kstride + hi8;
#pragma unroll
    for (int ks = 0; ks < 4; ++ks) kf[ks] = *(const bf16x8*)(kr + ks * 16);
  }

  for (int t = w; t < nt; t += 4) {
    const int kv0 = t * 32;
    // V^T fragments for tile t (issued early; consumed after softmax)
    bf16x8 vf[2][2];
#pragma unroll
    for (int mb = 0; mb < 2; ++mb)
#pragma unroll
      for (int ks = 0; ks < 2; ++ks)
        vf[mb][ks] = *(const bf16x8*)(vsrc + (size_t)(mb * 32 + ql) * vlen + kv0 + ks * 16 + hi8);
    // prefetch K for tile t+4
    if (t + 4 < nt) {
      const bf16_t* kr = ksrc + (size_t)(kvb + kv0 + 128 + ql) * kstride + hi8;
#pragma unroll
      for (int ks = 0; ks < 4; ++ks) nkf[ks] = *(const bf16x8*)(kr + ks * 16);
    }

    // S^T = K @ Q^T : C col = q = ql, row = kv = (r&3)+8*(r>>2)+kv4
    f32x16 sa = {};
    __builtin_amdgcn_s_setprio(1);
#pragma unroll
    for (int ks = 0; ks < 4; ++ks)
      sa = __builtin_amdgcn_mfma_f32_32x32x16_bf16(kf[ks], qf[ks], sa, 0, 0, 0);
    __builtin_amdgcn_s_setprio(0);

    float sv[16];
    const bool mt = is_self && (t == qt);  // diagonal tile
#pragma unroll
    for (int r = 0; r < 16; ++r) {
      float v = sa[r];
      if (mt) {
        int kvr = (r & 3) + 8 * (r >> 2) + kv4;
        v = (kvr > ql) ? -1e30f : v;
      }
      sv[r] = v;  // RAW units
    }
    float tm = fmaxf(
        fmaxf(fmaxf(fmaxf(sv[0], sv[1]), fmaxf(sv[2], sv[3])),
              fmaxf(fmaxf(sv[4], sv[5]), fmaxf(sv[6], sv[7]))),
        fmaxf(fmaxf(fmaxf(sv[8], sv[9]), fmaxf(sv[10], sv[11])),
              fmaxf(fmaxf(sv[12], sv[13]), fmaxf(sv[14], sv[15]))));
    tm = fmaxf(tm, __shfl_xor(tm, 32));

    if (!__all(tm <= mcur + 64.f)) {  // defer-max (64 raw = 8 scaled)
      float mn = fmaxf(mcur, tm);
      float sc = FEXP2((mcur - mn) * EXP2C);
      mcur = mn;
      lcur *= sc;
#pragma unroll
      for (int mb = 0; mb < 2; ++mb)
#pragma unroll
        for (int r = 0; r < 16; ++r) oacc[mb][r] *= sc;
    }

    const float hm = mcur * EXP2C;
    float pf[16];
#pragma unroll
    for (int r = 0; r < 16; ++r) pf[r] = FEXP2(__builtin_fmaf(sv[r], EXP2C, -hm));
    float ps = (((pf[0] + pf[1]) + (pf[2] + pf[3])) + ((pf[4] + pf[5]) + (pf[6] + pf[7]))) +
               (((pf[8] + pf[9]) + (pf[10] + pf[11])) + ((pf[12] + pf[13]) + (pf[14] + pf[15])));
    ps += __shfl_xor(ps, 32);
    lcur += ps;

    // P -> PV B-fragments, in-register (pack + half-wave exchange + select)
    unsigned o01 = pkbf(pf[0], pf[1]), o23 = pkbf(pf[2], pf[3]);
    unsigned o45 = pkbf(pf[4], pf[5]), o67 = pkbf(pf[6], pf[7]);
    unsigned o89 = pkbf(pf[8], pf[9]), o1011 = pkbf(pf[10], pf[11]);
    unsigned o1213 = pkbf(pf[12], pf[13]), o1415 = pkbf(pf[14], pf[15]);
    unsigned p01 = __shfl_xor(o01, 32), p23 = __shfl_xor(o23, 32);
    unsigned p45 = __shfl_xor(o45, 32), p67 = __shfl_xor(o67, 32);
    unsigned p89 = __shfl_xor(o89, 32), p1011 = __shfl_xor(o1011, 32);
    unsigned p1213 = __shfl_xor(o1213, 32), p1415 = __shfl_xor(o1415, 32);
    uint4 w0 = { uhi ? p45 : o01, uhi ? p67 : o23, uhi ? o45 : p01, uhi ? o67 : p23 };
    uint4 w1 = { uhi ? p1213 : o89, uhi ? p1415 : o1011, uhi ? o1213 : p89, uhi ? o1415 : p1011 };
    bf16x8 pb0 = __builtin_bit_cast(bf16x8, w0);
    bf16x8 pb1 = __builtin_bit_cast(bf16x8, w1);

    // O^T += V^T @ P : C col = q = ql, row = hd
    __builtin_amdgcn_s_setprio(1);
#pragma unroll
    for (int mb = 0; mb < 2; ++mb) {
      oacc[mb] = __builtin_amdgcn_mfma_f32_32x32x16_bf16(vf[mb][0], pb0, oacc[mb], 0, 0, 0);
      oacc[mb] = __builtin_amdgcn_mfma_f32_32x32x16_bf16(vf[mb][1], pb1, oacc[mb], 0, 0, 0);
    }
    __builtin_amdgcn_s_setprio(0);

    if (t + 4 < nt) {
#pragma unroll
      for (int ks = 0; ks < 4; ++ks) kf[ks] = nkf[ks];
    }
  }

  // ---- partial store: each wave dumps (O^T, m, l) to LDS ----
#pragma unroll
  for (int mb = 0; mb < 2; ++mb)
#pragma unroll
    for (int r = 0; r < 16; ++r)
      sO[w][mb * 16 + r][l] = oacc[mb][r];
  if (!uhi) { sO[w][32][ql] = mcur; sO[w][33][ql] = lcur; }
  __syncthreads();
  if (w != 0) return;

  // ---- merge 4 partials (wave 0) ----
  float m0 = sO[0][32][ql], m1 = sO[1][32][ql], m2 = sO[2][32][ql], m3 = sO[3][32][ql];
  float MM = fmaxf(fmaxf(m0, m1), fmaxf(m2, m3));
  float s0 = FEXP2((m0 - MM) * EXP2C), s1 = FEXP2((m1 - MM) * EXP2C);
  float s2 = FEXP2((m2 - MM) * EXP2C), s3 = FEXP2((m3 - MM) * EXP2C);
  float LL = sO[0][33][ql] * s0 + sO[1][33][ql] * s1 +
             sO[2][33][ql] * s2 + sO[3][33][ql] * s3;
  const float rl = 1.0f / LL;
  float mg[32];
#pragma unroll
  for (int j = 0; j < 32; ++j)
    mg[j] = (sO[0][j][l] * s0 + sO[1][j][l] * s1 + sO[2][j][l] * s2 + sO[3][j][l] * s3) * rl;

  // ---- normalize done; transpose O^T -> O via LDS, coalesced store ----
#pragma unroll
  for (int mb = 0; mb < 2; ++mb)
#pragma unroll
    for (int r2 = 0; r2 < 8; ++r2) {
      float lo = mg[mb * 16 + 2 * r2];
      float hiv = mg[mb * 16 + 2 * r2 + 1];
      int hdb = (r2 & 1) * 2 + 8 * (r2 >> 1) + kv4 + mb * 32;
      int off = (ql * 128 + hdb * 2) ^ ((ql & 7) << 4);
      *(unsigned*)(swb + off) = pkbf(lo, hiv);
    }
  const int orow = b * 2048 + ooff + q0;
#pragma unroll
  for (int it = 0; it < 4; ++it) {
    int idx = it * 64 + l;
    int q = idx >> 3, ch = idx & 7;
    int off = (q * 128 + ch * 16) ^ ((q & 7) << 4);
    uint4 d = *(uint4*)(swb + off);
    *(uint4*)&obuf[(size_t)(orow + q) * 1024 + hcol + ch * 8] = d;
  }
}

// ---------------------------------------------------------------------------
extern "C" void kernel_launch(void* const* d_in, const int* in_sizes, int n_in,
                              void* d_out, int out_size, void* d_ws, size_t ws_size,
                              hipStream_t stream) {
  (void)in_sizes; (void)n_in; (void)out_size; (void)ws_size;
  const float* x   = (const float*)d_in[0];
  const float* pkg = (const float*)d_in[1];
  const float* Wc  = (const float*)d_in[2];
  const float* bc  = (const float*)d_in[3];
  const float* Wk  = (const float*)d_in[4];
  const float* bk  = (const float*)d_in[5];
  const float* Wp  = (const float*)d_in[6];
  const float* bp  = (const float*)d_in[7];
  float* out = (float*)d_out;

  char* ws = (char*)d_ws;
  const size_t MB = 1u << 20;
  bf16_t* xb   = (bf16_t*)(ws + 0 * MB);   // [4096][1024]   8 MB
  bf16_t* pkb  = (bf16_t*)(ws + 8 * MB);   // [1024][1024]   2 MB
  bf16_t* Wct  = (bf16_t*)(ws + 10 * MB);  // [3072][1024]   6 MB
  bf16_t* Wkt  = (bf16_t*)(ws + 16 * MB);  // [2048][1024]   4 MB
  bf16_t* Wpt  = (bf16_t*)(ws + 20 * MB);  // [1024][1024]   2 MB
  bf16_t* kkvb = (bf16_t*)(ws + 22 * MB);  // [1024][2048]   4 MB
  bf16_t* abuf = (bf16_t*)(ws + 26 * MB);  // [8192][1024]  16 MB
  bf16_t* vTc  = (bf16_t*)(ws + 42 * MB);  // [64][64][256]  2 MB (ws total 44 MB)
  // d_out double-duty: qkv intermediate + self V^T; both dead before proj GEMM
  bf16_t* qkvb = (bf16_t*)d_out;                      // [4096][3072] 24 MB
  bf16_t* vTs  = (bf16_t*)((char*)d_out + 24 * MB);   // [64][64][1024] 8 MB

  cvt_kernel<<<4096, 256, 0, stream>>>(x, xb, 4096 * 1024 / 4);
  cvt_kernel<<<1024, 256, 0, stream>>>(pkg, pkb, 1024 * 1024 / 4);
  tcvt_kernel<<<dim3(3072 / 32, 1024 / 32), 256, 0, stream>>>(Wc, Wct, 1024, 3072);
  tcvt_kernel<<<dim3(2048 / 32, 1024 / 32), 256, 0, stream>>>(Wk, Wkt, 1024, 2048);
  tcvt_kernel<<<dim3(1024 / 32, 1024 / 32), 256, 0, stream>>>(Wp, Wpt, 1024, 1024);

  gemm_bt_kernel<0><<<dim3(24, 32), 256, 0, stream>>>(xb, Wct, bc, qkvb, 4096, 3072, 1024);
  gemm_bt_kernel<0><<<dim3(16, 8), 256, 0, stream>>>(pkb, Wkt, bk, kkvb, 1024, 2048, 1024);

  vtrans_kernel<<<dim3(16, 64), 256, 0, stream>>>(qkvb, vTs, 1024, 3072, 2048);
  vtrans_kernel<<<dim3(4, 64), 256, 0, stream>>>(kkvb, vTc, 256, 2048, 1024);

  attn_kernel<<<dim3(4096), 256, 0, stream>>>(qkvb, kkvb, vTs, vTc, abuf);

  gemm_bt_kernel<1><<<dim3(8, 64), 256, 0, stream>>>(abuf, Wpt, bp, out, 8192, 1024, 1024);
}

// Round 6
// 158.417 us; speedup vs baseline: 1.0880x; 1.0880x over previous
//
#include <hip/hip_runtime.h>
#include <hip/hip_bf16.h>

typedef __bf16 bf16_t;
typedef bf16_t bf16x8 __attribute__((ext_vector_type(8)));
typedef bf16_t bf16x4 __attribute__((ext_vector_type(4)));
typedef float f32x4 __attribute__((ext_vector_type(4)));
typedef float f32x16 __attribute__((ext_vector_type(16)));

#define EXP2C 0.1803368867f  // 0.125 * log2(e)
#define FEXP2(x) __builtin_amdgcn_exp2f(x)  // v_exp_f32 (base-2)

// async global->LDS, 16B per lane (dest must be wave-uniform base + lane*16)
__device__ __forceinline__ void gload16(const void* g, void* l) {
  __builtin_amdgcn_global_load_lds(
      (const __attribute__((address_space(1))) void*)g,
      (__attribute__((address_space(3))) void*)l, 16, 0, 0);
}

__device__ __forceinline__ unsigned pkbf(float lo, float hi) {
  unsigned short a = __builtin_bit_cast(unsigned short, (bf16_t)lo);
  unsigned short b = __builtin_bit_cast(unsigned short, (bf16_t)hi);
  return (unsigned)a | ((unsigned)b << 16);
}

// ---------------------------------------------------------------------------
// convert f32 -> bf16, vectorized
// ---------------------------------------------------------------------------
__global__ __launch_bounds__(256) void cvt_kernel(const float* __restrict__ in,
                                                  bf16_t* __restrict__ out, int n4) {
  int i = blockIdx.x * 256 + threadIdx.x;
  if (i >= n4) return;
  float4 v = reinterpret_cast<const float4*>(in)[i];
  bf16x4 o = { (bf16_t)v.x, (bf16_t)v.y, (bf16_t)v.z, (bf16_t)v.w };
  reinterpret_cast<bf16x4*>(out)[i] = o;
}

// ---------------------------------------------------------------------------
// transpose + convert: W[K][N] f32 -> Wt[N][K] bf16
// ---------------------------------------------------------------------------
__global__ __launch_bounds__(256) void tcvt_kernel(const float* __restrict__ W,
                                                   bf16_t* __restrict__ Wt,
                                                   int K, int N) {
  __shared__ float tile[32][33];
  int tx = threadIdx.x & 31, ty = threadIdx.x >> 5;
  int n0 = blockIdx.x * 32, k0 = blockIdx.y * 32;
#pragma unroll
  for (int i = 0; i < 4; ++i)
    tile[ty + i * 8][tx] = W[(size_t)(k0 + ty + i * 8) * N + n0 + tx];
  __syncthreads();
#pragma unroll
  for (int i = 0; i < 4; ++i)
    Wt[(size_t)(n0 + ty + i * 8) * K + k0 + tx] = (bf16_t)tile[tx][ty + i * 8];
}

// ---------------------------------------------------------------------------
// Pack K and V of one (bh, kv-tile) into MFMA fragment order:
//   kdst[((bh*NT+t)*4+ks)*512 + l*8 + j] = K[kv0+(l&31)][ks*16+(l>=32?8:0)+j]
//   vdst[((bh*NT+t)*4+(mb*2+ks))*512 + l*8 + j]
//       = V[kv0+ks*16+(l>=32?8:0)+j][mb*32+(l&31)]   (V^T fragment)
// Attn then loads fragments as fully-coalesced contiguous 1KB wave reads.
// ---------------------------------------------------------------------------
__global__ __launch_bounds__(256) void pack_kernel(
    const bf16_t* __restrict__ src, bf16_t* __restrict__ kdst,
    bf16_t* __restrict__ vdst, int R, int stride, int kcol, int vcol) {
  __shared__ bf16_t vt[32][72];  // row stride 144B (16B-aligned)
  const int tid = threadIdx.x;
  const int t = blockIdx.x, bh = blockIdx.y;
  const int NT = gridDim.x;
  const int b = bh >> 4, h = bh & 15;
  const size_t srow = (size_t)b * R + t * 32;
  const size_t obase = ((size_t)bh * NT + t) * 2048;
  // V tile -> LDS (rows=kv, cols=hd)
  {
    int r = tid >> 3, c = tid & 7;
    bf16x8 d = *(const bf16x8*)&src[(srow + r) * stride + vcol + h * 64 + c * 8];
    *(bf16x8*)&vt[r][c * 8] = d;
  }
  // K fragments: direct global->global
  {
    int ks = tid >> 6, l = tid & 63;
    int hi8 = (l >> 5) * 8;
    bf16x8 d = *(const bf16x8*)&src[(srow + (l & 31)) * stride + kcol + h * 64 + ks * 16 + hi8];
    *(bf16x8*)&kdst[obase + ks * 512 + l * 8] = d;
  }
  __syncthreads();
  // V^T fragments from LDS
  {
    int dd = tid >> 6, l = tid & 63;
    int mb = dd >> 1, ks = dd & 1;
    int hd = mb * 32 + (l & 31);
    int kvr = ks * 16 + (l >> 5) * 8;
    bf16x8 o;
#pragma unroll
    for (int j = 0; j < 8; ++j) o[j] = vt[kvr + j][hd];
    *(bf16x8*)&vdst[obase + dd * 512 + l * 8] = o;
  }
}

// ---------------------------------------------------------------------------
// GEMM: C[M][N] = A[M][K] @ Bt[N][K]^T + bias.  128x128 tile, BK=32,
// 4 waves, 4x4 mfma_f32_16x16x32_bf16.  3-buffer global_load_lds pipeline
// with counted vmcnt (T4): stage(t+2) issued before compute(t); barrier
// waits only for stage(t+1) (vmcnt(4)), never draining the newest loads.
// ---------------------------------------------------------------------------
template <int OUTF32>
__global__ __launch_bounds__(256) void gemm_bt_kernel(
    const bf16_t* __restrict__ A, const bf16_t* __restrict__ Bt,
    const float* __restrict__ bias, void* __restrict__ Cout,
    int M, int N, int K) {
  __shared__ __align__(16) bf16_t sA[3][128 * 32];
  __shared__ __align__(16) bf16_t sB[3][128 * 32];
  const int tid = threadIdx.x;
  const int l = tid & 63, w = tid >> 6;
  const int lr = l & 15, lg = l >> 4;
  const int m0 = blockIdx.y * 128, n0 = blockIdx.x * 128;
  const int wr = (w >> 1) * 64, wc = (w & 1) * 64;

  const int i0 = tid, i1 = tid + 256;
  const bf16_t* ga0 = A + (size_t)(m0 + (i0 >> 2)) * K + (i0 & 3) * 8;
  const bf16_t* ga1 = A + (size_t)(m0 + (i1 >> 2)) * K + (i1 & 3) * 8;
  const bf16_t* gb0 = Bt + (size_t)(n0 + (i0 >> 2)) * K + (i0 & 3) * 8;
  const bf16_t* gb1 = Bt + (size_t)(n0 + (i1 >> 2)) * K + (i1 & 3) * 8;

  f32x4 acc[4][4] = {};
  const int nk = K >> 5;

  auto STAGE = [&](int buf, int kt2) {
    const int ko = kt2 * 32;
    gload16(ga0 + ko, &sA[buf][i0 * 8]);
    gload16(ga1 + ko, &sA[buf][i1 * 8]);
    gload16(gb0 + ko, &sB[buf][i0 * 8]);
    gload16(gb1 + ko, &sB[buf][i1 * 8]);
  };

  STAGE(0, 0);
  STAGE(1, 1);
  asm volatile("s_waitcnt vmcnt(4)" ::: "memory");  // buf0 landed; buf1 in flight
  __builtin_amdgcn_s_barrier();

  int cur = 0;
  for (int kt = 0; kt < nk; ++kt) {
    int fut = cur + 2; if (fut >= 3) fut -= 3;
    const bool more = (kt + 2 < nk);
    if (more) STAGE(fut, kt + 2);

    bf16x8 af[4], bv[4];
#pragma unroll
    for (int mf = 0; mf < 4; ++mf)
      af[mf] = *(const bf16x8*)&sA[cur][(wr + mf * 16 + lr) * 32 + lg * 8];
#pragma unroll
    for (int nf = 0; nf < 4; ++nf)
      bv[nf] = *(const bf16x8*)&sB[cur][(wc + nf * 16 + lr) * 32 + lg * 8];
    __builtin_amdgcn_s_setprio(1);
#pragma unroll
    for (int mf = 0; mf < 4; ++mf)
#pragma unroll
      for (int nf = 0; nf < 4; ++nf)
        acc[mf][nf] = __builtin_amdgcn_mfma_f32_16x16x32_bf16(af[mf], bv[nf], acc[mf][nf], 0, 0, 0);
    __builtin_amdgcn_s_setprio(0);

    if (more) asm volatile("s_waitcnt vmcnt(4)" ::: "memory");  // buf[kt+1] landed
    else      asm volatile("s_waitcnt vmcnt(0)" ::: "memory");  // tail drain
    __builtin_amdgcn_s_barrier();
    cur = cur + 1; if (cur >= 3) cur -= 3;
  }

#pragma unroll
  for (int mf = 0; mf < 4; ++mf) {
#pragma unroll
    for (int nf = 0; nf < 4; ++nf) {
      int col = n0 + wc + nf * 16 + lr;
      float bb = bias[col];
      int rowb = m0 + wr + mf * 16 + lg * 4;
#pragma unroll
      for (int r = 0; r < 4; ++r) {
        float v = acc[mf][nf][r] + bb;
        if constexpr (OUTF32)
          ((float*)Cout)[(size_t)(rowb + r) * N + col] = v;
        else
          ((bf16_t*)Cout)[(size_t)(rowb + r) * N + col] = (bf16_t)v;
      }
    }
  }
}

// ---------------------------------------------------------------------------
// Unified flash attention, intra-block split-KV, fragment-packed K/V.
// One BLOCK = one (bh, q-tile); 4 waves take interleaved kv-tiles (t=w,w+4,..)
// with private (m,l,O^T); LDS merge at the end (exact). K and V fragments are
// read from pre-packed buffers as contiguous 1KB coalesced wave loads, both
// prefetched one split-iteration ahead. Swapped QK^T; raw-domain softmax;
// P stays in registers.
// ---------------------------------------------------------------------------
__global__ __launch_bounds__(256, 2) void attn_kernel(
    const bf16_t* __restrict__ qkv,   // [4096][3072] (q at hcol)
    const bf16_t* __restrict__ kfs, const bf16_t* __restrict__ vfs,  // self packed
    const bf16_t* __restrict__ kfc, const bf16_t* __restrict__ vfc,  // cross packed
    bf16_t* __restrict__ obuf) {      // [8192][1024]
  __shared__ float sO[4][34][66];           // [wave][32 acc + m + l][lane]
  __shared__ __align__(16) char swb[4096];  // wave-0 output staging

  const int tid = threadIdx.x;
  const int w = tid >> 6, l = tid & 63;
  const int ql = l & 31;
  const bool uhi = l >= 32;
  const int kv4 = uhi ? 4 : 0;
  const int hi8 = uhi ? 8 : 0;

  const int bid = blockIdx.x;
  const bool is_self = bid < 2048;
  int qt, bh, nt;
  if (is_self) {  // heaviest q-tiles (qt=31) dispatch first
    qt = 31 - (bid >> 6);
    bh = bid & 63;
    nt = qt + 1;
  } else {
    int cb = bid - 2048;
    qt = cb >> 6;
    bh = cb & 63;
    nt = 8;
  }
  const int b = bh >> 4, h = bh & 15;
  const int hcol = h * 64;
  const int q0 = qt * 32;

  const bf16_t* kba; const bf16_t* vba; int ooff;
  if (is_self) {
    kba = kfs + (size_t)bh * 32 * 2048; vba = vfs + (size_t)bh * 32 * 2048; ooff = 0;
  } else {
    kba = kfc + (size_t)bh * 8 * 2048;  vba = vfc + (size_t)bh * 8 * 2048;  ooff = 1024;
  }

  // Q fragments (B-operand): lane holds col q = ql, k = hd = ks*16 + hi8 + j
  const bf16_t* qrow = qkv + (size_t)(b * 1024 + q0 + ql) * 3072 + hcol + hi8;
  bf16x8 qf[4];
#pragma unroll
  for (int ks = 0; ks < 4; ++ks) qf[ks] = *(const bf16x8*)(qrow + ks * 16);

  float mcur = -1e30f, lcur = 0.f;  // RAW (pre-scale) units
  f32x16 oacc[2] = {};

  bf16x8 kf[4], vf[4], nkf[4], nvf[4];
  if (w < nt) {
#pragma unroll
    for (int c = 0; c < 4; ++c) kf[c] = *(const bf16x8*)(kba + (size_t)w * 2048 + c * 512 + l * 8);
#pragma unroll
    for (int c = 0; c < 4; ++c) vf[c] = *(const bf16x8*)(vba + (size_t)w * 2048 + c * 512 + l * 8);
  }

  for (int t = w; t < nt; t += 4) {
    if (t + 4 < nt) {  // prefetch next split-iteration's K and V fragments
#pragma unroll
      for (int c = 0; c < 4; ++c) nkf[c] = *(const bf16x8*)(kba + (size_t)(t + 4) * 2048 + c * 512 + l * 8);
#pragma unroll
      for (int c = 0; c < 4; ++c) nvf[c] = *(const bf16x8*)(vba + (size_t)(t + 4) * 2048 + c * 512 + l * 8);
    }

    // S^T = K @ Q^T : C col = q = ql, row = kv = (r&3)+8*(r>>2)+kv4
    f32x16 sa = {};
    __builtin_amdgcn_s_setprio(1);
#pragma unroll
    for (int ks = 0; ks < 4; ++ks)
      sa = __builtin_amdgcn_mfma_f32_32x32x16_bf16(kf[ks], qf[ks], sa, 0, 0, 0);
    __builtin_amdgcn_s_setprio(0);

    float sv[16];
    const bool mt = is_self && (t == qt);  // diagonal tile
#pragma unroll
    for (int r = 0; r < 16; ++r) {
      float v = sa[r];
      if (mt) {
        int kvr = (r & 3) + 8 * (r >> 2) + kv4;
        v = (kvr > ql) ? -1e30f : v;
      }
      sv[r] = v;
    }
    float tm = fmaxf(
        fmaxf(fmaxf(fmaxf(sv[0], sv[1]), fmaxf(sv[2], sv[3])),
              fmaxf(fmaxf(sv[4], sv[5]), fmaxf(sv[6], sv[7]))),
        fmaxf(fmaxf(fmaxf(sv[8], sv[9]), fmaxf(sv[10], sv[11])),
              fmaxf(fmaxf(sv[12], sv[13]), fmaxf(sv[14], sv[15]))));
    tm = fmaxf(tm, __shfl_xor(tm, 32));

    if (!__all(tm <= mcur + 64.f)) {  // defer-max (64 raw = 8 scaled)
      float mn = fmaxf(mcur, tm);
      float sc = FEXP2((mcur - mn) * EXP2C);
      mcur = mn;
      lcur *= sc;
#pragma unroll
      for (int mb = 0; mb < 2; ++mb)
#pragma unroll
        for (int r = 0; r < 16; ++r) oacc[mb][r] *= sc;
    }

    const float hm = mcur * EXP2C;
    float pf[16];
#pragma unroll
    for (int r = 0; r < 16; ++r) pf[r] = FEXP2(__builtin_fmaf(sv[r], EXP2C, -hm));
    float ps = (((pf[0] + pf[1]) + (pf[2] + pf[3])) + ((pf[4] + pf[5]) + (pf[6] + pf[7]))) +
               (((pf[8] + pf[9]) + (pf[10] + pf[11])) + ((pf[12] + pf[13]) + (pf[14] + pf[15])));
    ps += __shfl_xor(ps, 32);
    lcur += ps;

    // P -> PV B-fragments, in-register (pack + half-wave exchange + select)
    unsigned o01 = pkbf(pf[0], pf[1]), o23 = pkbf(pf[2], pf[3]);
    unsigned o45 = pkbf(pf[4], pf[5]), o67 = pkbf(pf[6], pf[7]);
    unsigned o89 = pkbf(pf[8], pf[9]), o1011 = pkbf(pf[10], pf[11]);
    unsigned o1213 = pkbf(pf[12], pf[13]), o1415 = pkbf(pf[14], pf[15]);
    unsigned p01 = __shfl_xor(o01, 32), p23 = __shfl_xor(o23, 32);
    unsigned p45 = __shfl_xor(o45, 32), p67 = __shfl_xor(o67, 32);
    unsigned p89 = __shfl_xor(o89, 32), p1011 = __shfl_xor(o1011, 32);
    unsigned p1213 = __shfl_xor(o1213, 32), p1415 = __shfl_xor(o1415, 32);
    uint4 w0 = { uhi ? p45 : o01, uhi ? p67 : o23, uhi ? o45 : p01, uhi ? o67 : p23 };
    uint4 w1 = { uhi ? p1213 : o89, uhi ? p1415 : o1011, uhi ? o1213 : p89, uhi ? o1415 : p1011 };
    bf16x8 pb0 = __builtin_bit_cast(bf16x8, w0);
    bf16x8 pb1 = __builtin_bit_cast(bf16x8, w1);

    // O^T += V^T @ P : C col = q = ql, row = hd
    __builtin_amdgcn_s_setprio(1);
#pragma unroll
    for (int mb = 0; mb < 2; ++mb) {
      oacc[mb] = __builtin_amdgcn_mfma_f32_32x32x16_bf16(vf[mb * 2 + 0], pb0, oacc[mb], 0, 0, 0);
      oacc[mb] = __builtin_amdgcn_mfma_f32_32x32x16_bf16(vf[mb * 2 + 1], pb1, oacc[mb], 0, 0, 0);
    }
    __builtin_amdgcn_s_setprio(0);

    if (t + 4 < nt) {
#pragma unroll
      for (int c = 0; c < 4; ++c) { kf[c] = nkf[c]; vf[c] = nvf[c]; }
    }
  }

  // ---- partial store: each wave dumps (O^T, m, l) to LDS ----
#pragma unroll
  for (int mb = 0; mb < 2; ++mb)
#pragma unroll
    for (int r = 0; r < 16; ++r)
      sO[w][mb * 16 + r][l] = oacc[mb][r];
  if (!uhi) { sO[w][32][ql] = mcur; sO[w][33][ql] = lcur; }
  __syncthreads();
  if (w != 0) return;

  // ---- merge 4 partials (wave 0) ----
  float m0 = sO[0][32][ql], m1 = sO[1][32][ql], m2 = sO[2][32][ql], m3 = sO[3][32][ql];
  float MM = fmaxf(fmaxf(m0, m1), fmaxf(m2, m3));
  float s0 = FEXP2((m0 - MM) * EXP2C), s1 = FEXP2((m1 - MM) * EXP2C);
  float s2 = FEXP2((m2 - MM) * EXP2C), s3 = FEXP2((m3 - MM) * EXP2C);
  float LL = sO[0][33][ql] * s0 + sO[1][33][ql] * s1 +
             sO[2][33][ql] * s2 + sO[3][33][ql] * s3;
  const float rl = 1.0f / LL;
  float mg[32];
#pragma unroll
  for (int j = 0; j < 32; ++j)
    mg[j] = (sO[0][j][l] * s0 + sO[1][j][l] * s1 + sO[2][j][l] * s2 + sO[3][j][l] * s3) * rl;

  // ---- transpose O^T -> O via LDS, coalesced store ----
#pragma unroll
  for (int mb = 0; mb < 2; ++mb)
#pragma unroll
    for (int r2 = 0; r2 < 8; ++r2) {
      float lo = mg[mb * 16 + 2 * r2];
      float hiv = mg[mb * 16 + 2 * r2 + 1];
      int hdb = (r2 & 1) * 2 + 8 * (r2 >> 1) + kv4 + mb * 32;
      int off = (ql * 128 + hdb * 2) ^ ((ql & 7) << 4);
      *(unsigned*)(swb + off) = pkbf(lo, hiv);
    }
  const int orow = b * 2048 + ooff + q0;
#pragma unroll
  for (int it = 0; it < 4; ++it) {
    int idx = it * 64 + l;
    int q = idx >> 3, ch = idx & 7;
    int off = (q * 128 + ch * 16) ^ ((q & 7) << 4);
    uint4 d = *(uint4*)(swb + off);
    *(uint4*)&obuf[(size_t)(orow + q) * 1024 + hcol + ch * 8] = d;
  }
}

// ---------------------------------------------------------------------------
extern "C" void kernel_launch(void* const* d_in, const int* in_sizes, int n_in,
                              void* d_out, int out_size, void* d_ws, size_t ws_size,
                              hipStream_t stream) {
  (void)in_sizes; (void)n_in; (void)out_size; (void)ws_size;
  const float* x   = (const float*)d_in[0];
  const float* pkg = (const float*)d_in[1];
  const float* Wc  = (const float*)d_in[2];
  const float* bc  = (const float*)d_in[3];
  const float* Wk  = (const float*)d_in[4];
  const float* bk  = (const float*)d_in[5];
  const float* Wp  = (const float*)d_in[6];
  const float* bp  = (const float*)d_in[7];
  float* out = (float*)d_out;

  char* ws = (char*)d_ws;
  const size_t MB = 1u << 20;
  bf16_t* xb   = (bf16_t*)(ws + 0 * MB);   // [4096][1024]   8 MB (dead after qkv GEMM)
  bf16_t* pkb  = (bf16_t*)(ws + 8 * MB);   // [1024][1024]   2 MB (dead after kkv GEMM)
  bf16_t* Wct  = (bf16_t*)(ws + 10 * MB);  // [3072][1024]   6 MB (dead after qkv GEMM)
  bf16_t* Wkt  = (bf16_t*)(ws + 16 * MB);  // [2048][1024]   4 MB
  bf16_t* Wpt  = (bf16_t*)(ws + 20 * MB);  // [1024][1024]   2 MB
  bf16_t* kkvb = (bf16_t*)(ws + 22 * MB);  // [1024][2048]   4 MB
  bf16_t* abuf = (bf16_t*)(ws + 26 * MB);  // [8192][1024]  16 MB  (ws total 42 MB)
  bf16_t* vfs  = (bf16_t*)(ws + 0 * MB);   // packed self V^T frags  8 MB (reuses xb)
  bf16_t* kfc  = (bf16_t*)(ws + 8 * MB);   // packed cross K frags   2 MB (reuses pkb)
  bf16_t* vfc  = (bf16_t*)(ws + 10 * MB);  // packed cross V^T frags 2 MB (reuses Wct)
  // d_out double-duty: qkv intermediate + packed self K frags
  bf16_t* qkvb = (bf16_t*)d_out;                      // [4096][3072] 24 MB
  bf16_t* kfs  = (bf16_t*)((char*)d_out + 24 * MB);   // packed self K frags 8 MB

  cvt_kernel<<<4096, 256, 0, stream>>>(x, xb, 4096 * 1024 / 4);
  cvt_kernel<<<1024, 256, 0, stream>>>(pkg, pkb, 1024 * 1024 / 4);
  tcvt_kernel<<<dim3(3072 / 32, 1024 / 32), 256, 0, stream>>>(Wc, Wct, 1024, 3072);
  tcvt_kernel<<<dim3(2048 / 32, 1024 / 32), 256, 0, stream>>>(Wk, Wkt, 1024, 2048);
  tcvt_kernel<<<dim3(1024 / 32, 1024 / 32), 256, 0, stream>>>(Wp, Wpt, 1024, 1024);

  gemm_bt_kernel<0><<<dim3(24, 32), 256, 0, stream>>>(xb, Wct, bc, qkvb, 4096, 3072, 1024);
  gemm_bt_kernel<0><<<dim3(16, 8), 256, 0, stream>>>(pkb, Wkt, bk, kkvb, 1024, 2048, 1024);

  // fragment-order packing (K and V^T), self then cross
  pack_kernel<<<dim3(32, 64), 256, 0, stream>>>(qkvb, kfs, vfs, 1024, 3072, 1024, 2048);
  pack_kernel<<<dim3(8, 64), 256, 0, stream>>>(kkvb, kfc, vfc, 256, 2048, 0, 1024);

  attn_kernel<<<dim3(4096), 256, 0, stream>>>(qkvb, kfs, vfs, kfc, vfc, abuf);

  gemm_bt_kernel<1><<<dim3(8, 64), 256, 0, stream>>>(abuf, Wpt, bp, out, 8192, 1024, 1024);
}

// Round 7
// 156.792 us; speedup vs baseline: 1.0993x; 1.0104x over previous
//
#include <hip/hip_runtime.h>
#include <hip/hip_bf16.h>

typedef __bf16 bf16_t;
typedef bf16_t bf16x8 __attribute__((ext_vector_type(8)));
typedef bf16_t bf16x4 __attribute__((ext_vector_type(4)));
typedef float f32x4 __attribute__((ext_vector_type(4)));
typedef float f32x16 __attribute__((ext_vector_type(16)));

#define EXP2C 0.1803368867f  // 0.125 * log2(e)
#define FEXP2(x) __builtin_amdgcn_exp2f(x)  // v_exp_f32 (base-2)

// async global->LDS, 16B per lane (dest must be wave-uniform base + lane*16)
__device__ __forceinline__ void gload16(const void* g, void* l) {
  __builtin_amdgcn_global_load_lds(
      (const __attribute__((address_space(1))) void*)g,
      (__attribute__((address_space(3))) void*)l, 16, 0, 0);
}

__device__ __forceinline__ unsigned pkbf(float lo, float hi) {
  unsigned short a = __builtin_bit_cast(unsigned short, (bf16_t)lo);
  unsigned short b = __builtin_bit_cast(unsigned short, (bf16_t)hi);
  return (unsigned)a | ((unsigned)b << 16);
}

// ---------------------------------------------------------------------------
// convert f32 -> bf16, vectorized
// ---------------------------------------------------------------------------
__global__ __launch_bounds__(256) void cvt_kernel(const float* __restrict__ in,
                                                  bf16_t* __restrict__ out, int n4) {
  int i = blockIdx.x * 256 + threadIdx.x;
  if (i >= n4) return;
  float4 v = reinterpret_cast<const float4*>(in)[i];
  bf16x4 o = { (bf16_t)v.x, (bf16_t)v.y, (bf16_t)v.z, (bf16_t)v.w };
  reinterpret_cast<bf16x4*>(out)[i] = o;
}

// ---------------------------------------------------------------------------
// transpose + convert: W[K][N] f32 -> Wt[N][K] bf16
// ---------------------------------------------------------------------------
__global__ __launch_bounds__(256) void tcvt_kernel(const float* __restrict__ W,
                                                   bf16_t* __restrict__ Wt,
                                                   int K, int N) {
  __shared__ float tile[32][33];
  int tx = threadIdx.x & 31, ty = threadIdx.x >> 5;
  int n0 = blockIdx.x * 32, k0 = blockIdx.y * 32;
#pragma unroll
  for (int i = 0; i < 4; ++i)
    tile[ty + i * 8][tx] = W[(size_t)(k0 + ty + i * 8) * N + n0 + tx];
  __syncthreads();
#pragma unroll
  for (int i = 0; i < 4; ++i)
    Wt[(size_t)(n0 + ty + i * 8) * K + k0 + tx] = (bf16_t)tile[tx][ty + i * 8];
}

// ---------------------------------------------------------------------------
// Pack K and V of one (bh, kv-tile) into MFMA fragment order (1KB/frag-chunk).
// ---------------------------------------------------------------------------
__global__ __launch_bounds__(256) void pack_kernel(
    const bf16_t* __restrict__ src, bf16_t* __restrict__ kdst,
    bf16_t* __restrict__ vdst, int R, int stride, int kcol, int vcol) {
  __shared__ bf16_t vt[32][72];  // row stride 144B (16B-aligned)
  const int tid = threadIdx.x;
  const int t = blockIdx.x, bh = blockIdx.y;
  const int NT = gridDim.x;
  const int b = bh >> 4, h = bh & 15;
  const size_t srow = (size_t)b * R + t * 32;
  const size_t obase = ((size_t)bh * NT + t) * 2048;
  // V tile -> LDS (rows=kv, cols=hd)
  {
    int r = tid >> 3, c = tid & 7;
    bf16x8 d = *(const bf16x8*)&src[(srow + r) * stride + vcol + h * 64 + c * 8];
    *(bf16x8*)&vt[r][c * 8] = d;
  }
  // K fragments: direct global->global
  {
    int ks = tid >> 6, l = tid & 63;
    int hi8 = (l >> 5) * 8;
    bf16x8 d = *(const bf16x8*)&src[(srow + (l & 31)) * stride + kcol + h * 64 + ks * 16 + hi8];
    *(bf16x8*)&kdst[obase + ks * 512 + l * 8] = d;
  }
  __syncthreads();
  // V^T fragments from LDS
  {
    int dd = tid >> 6, l = tid & 63;
    int mb = dd >> 1, ks = dd & 1;
    int hd = mb * 32 + (l & 31);
    int kvr = ks * 16 + (l >> 5) * 8;
    bf16x8 o;
#pragma unroll
    for (int j = 0; j < 8; ++j) o[j] = vt[kvr + j][hd];
    *(bf16x8*)&vdst[obase + dd * 512 + l * 8] = o;
  }
}

// ---------------------------------------------------------------------------
// GEMM: C[M][N] = A[M][K] @ Bt[N][K]^T + bias.  128x128 tile, BK=32,
// 4 waves, 4x4 mfma_f32_16x16x32_bf16. 2-phase double-buffered
// global_load_lds staging (R5 proven config).
// ---------------------------------------------------------------------------
template <int OUTF32>
__global__ __launch_bounds__(256) void gemm_bt_kernel(
    const bf16_t* __restrict__ A, const bf16_t* __restrict__ Bt,
    const float* __restrict__ bias, void* __restrict__ Cout,
    int M, int N, int K) {
  __shared__ __align__(16) bf16_t sA[2][128 * 32];
  __shared__ __align__(16) bf16_t sB[2][128 * 32];
  const int tid = threadIdx.x;
  const int l = tid & 63, w = tid >> 6;
  const int lr = l & 15, lg = l >> 4;
  const int m0 = blockIdx.y * 128, n0 = blockIdx.x * 128;
  const int wr = (w >> 1) * 64, wc = (w & 1) * 64;

  const int i0 = tid, i1 = tid + 256;
  const bf16_t* ga0 = A + (size_t)(m0 + (i0 >> 2)) * K + (i0 & 3) * 8;
  const bf16_t* ga1 = A + (size_t)(m0 + (i1 >> 2)) * K + (i1 & 3) * 8;
  const bf16_t* gb0 = Bt + (size_t)(n0 + (i0 >> 2)) * K + (i0 & 3) * 8;
  const bf16_t* gb1 = Bt + (size_t)(n0 + (i1 >> 2)) * K + (i1 & 3) * 8;

  f32x4 acc[4][4] = {};

  const int nk = K >> 5;
  gload16(ga0, &sA[0][i0 * 8]);
  gload16(ga1, &sA[0][i1 * 8]);
  gload16(gb0, &sB[0][i0 * 8]);
  gload16(gb1, &sB[0][i1 * 8]);
  __syncthreads();

  int cur = 0;
  for (int kt = 0; kt < nk; ++kt) {
    if (kt + 1 < nk) {
      const int ko = (kt + 1) * 32;
      gload16(ga0 + ko, &sA[cur ^ 1][i0 * 8]);
      gload16(ga1 + ko, &sA[cur ^ 1][i1 * 8]);
      gload16(gb0 + ko, &sB[cur ^ 1][i0 * 8]);
      gload16(gb1 + ko, &sB[cur ^ 1][i1 * 8]);
    }
    bf16x8 af[4], bv[4];
#pragma unroll
    for (int mf = 0; mf < 4; ++mf)
      af[mf] = *(const bf16x8*)&sA[cur][(wr + mf * 16 + lr) * 32 + lg * 8];
#pragma unroll
    for (int nf = 0; nf < 4; ++nf)
      bv[nf] = *(const bf16x8*)&sB[cur][(wc + nf * 16 + lr) * 32 + lg * 8];
#pragma unroll
    for (int mf = 0; mf < 4; ++mf)
#pragma unroll
      for (int nf = 0; nf < 4; ++nf)
        acc[mf][nf] = __builtin_amdgcn_mfma_f32_16x16x32_bf16(af[mf], bv[nf], acc[mf][nf], 0, 0, 0);
    __syncthreads();
    cur ^= 1;
  }

#pragma unroll
  for (int mf = 0; mf < 4; ++mf) {
#pragma unroll
    for (int nf = 0; nf < 4; ++nf) {
      int col = n0 + wc + nf * 16 + lr;
      float bb = bias[col];
      int rowb = m0 + wr + mf * 16 + lg * 4;
#pragma unroll
      for (int r = 0; r < 4; ++r) {
        float v = acc[mf][nf][r] + bb;
        if constexpr (OUTF32)
          ((float*)Cout)[(size_t)(rowb + r) * N + col] = v;
        else
          ((bf16_t*)Cout)[(size_t)(rowb + r) * N + col] = (bf16_t)v;
      }
    }
  }
}

// ---------------------------------------------------------------------------
// Flash attention, intra-block split-KV, fragment-packed K/V, software-
// pipelined: QK^T(t+4) issued at END of iteration t (K loaded at top of the
// same iteration -> softmax+PV covers the load latency; next softmax stalls
// only on the QK chain tail). V double-buffered via unroll-2 (static idx).
// Distributed 4-wave merge epilogue. LDS 34816 B, 3 blocks/CU target.
// ---------------------------------------------------------------------------
#define LOADK(t)                                                             \
  {                                                                          \
    _Pragma("unroll") for (int c = 0; c < 4; ++c)                            \
        kf[c] = *(const bf16x8*)(kba + (size_t)(t) * 2048 + c * 512 + l * 8);\
  }
#define LOADV(vf, t)                                                         \
  {                                                                          \
    _Pragma("unroll") for (int c = 0; c < 4; ++c)                            \
        vf[c] = *(const bf16x8*)(vba + (size_t)(t) * 2048 + c * 512 + l * 8);\
  }
#define QKT()                                                                \
  {                                                                          \
    sa = (f32x16){};                                                         \
    __builtin_amdgcn_s_setprio(1);                                           \
    _Pragma("unroll") for (int ks = 0; ks < 4; ++ks)                         \
        sa = __builtin_amdgcn_mfma_f32_32x32x16_bf16(kf[ks], qf[ks], sa, 0, 0, 0); \
    __builtin_amdgcn_s_setprio(0);                                           \
  }
#define SMPV(vf, tcur)                                                       \
  {                                                                          \
    float sv[16];                                                            \
    const bool mt = is_self && ((tcur) == qt);                               \
    _Pragma("unroll") for (int r = 0; r < 16; ++r) {                         \
      float v = sa[r];                                                       \
      if (mt) {                                                              \
        int kvr = (r & 3) + 8 * (r >> 2) + kv4;                              \
        v = (kvr > ql) ? -1e30f : v;                                         \
      }                                                                      \
      sv[r] = v;                                                             \
    }                                                                        \
    float tm = fmaxf(                                                        \
        fmaxf(fmaxf(fmaxf(sv[0], sv[1]), fmaxf(sv[2], sv[3])),               \
              fmaxf(fmaxf(sv[4], sv[5]), fmaxf(sv[6], sv[7]))),              \
        fmaxf(fmaxf(fmaxf(sv[8], sv[9]), fmaxf(sv[10], sv[11])),             \
              fmaxf(fmaxf(sv[12], sv[13]), fmaxf(sv[14], sv[15]))));         \
    tm = fmaxf(tm, __shfl_xor(tm, 32));                                      \
    if (!__all(tm <= mcur + 64.f)) {                                         \
      float mn = fmaxf(mcur, tm);                                            \
      float sc = FEXP2((mcur - mn) * EXP2C);                                 \
      mcur = mn;                                                             \
      lcur *= sc;                                                            \
      _Pragma("unroll") for (int mb = 0; mb < 2; ++mb)                       \
          _Pragma("unroll") for (int r = 0; r < 16; ++r) oacc[mb][r] *= sc;  \
    }                                                                        \
    const float hm = mcur * EXP2C;                                           \
    float pf[16];                                                            \
    _Pragma("unroll") for (int r = 0; r < 16; ++r)                           \
        pf[r] = FEXP2(__builtin_fmaf(sv[r], EXP2C, -hm));                    \
    float ps = (((pf[0] + pf[1]) + (pf[2] + pf[3])) +                        \
                ((pf[4] + pf[5]) + (pf[6] + pf[7]))) +                       \
               (((pf[8] + pf[9]) + (pf[10] + pf[11])) +                      \
                ((pf[12] + pf[13]) + (pf[14] + pf[15])));                    \
    ps += __shfl_xor(ps, 32);                                                \
    lcur += ps;                                                              \
    unsigned o01 = pkbf(pf[0], pf[1]), o23 = pkbf(pf[2], pf[3]);             \
    unsigned o45 = pkbf(pf[4], pf[5]), o67 = pkbf(pf[6], pf[7]);             \
    unsigned o89 = pkbf(pf[8], pf[9]), o1011 = pkbf(pf[10], pf[11]);         \
    unsigned o1213 = pkbf(pf[12], pf[13]), o1415 = pkbf(pf[14], pf[15]);     \
    unsigned p01 = __shfl_xor(o01, 32), p23 = __shfl_xor(o23, 32);           \
    unsigned p45 = __shfl_xor(o45, 32), p67 = __shfl_xor(o67, 32);           \
    unsigned p89 = __shfl_xor(o89, 32), p1011 = __shfl_xor(o1011, 32);       \
    unsigned p1213 = __shfl_xor(o1213, 32), p1415 = __shfl_xor(o1415, 32);   \
    uint4 w0 = { uhi ? p45 : o01, uhi ? p67 : o23, uhi ? o45 : p01, uhi ? o67 : p23 }; \
    uint4 w1 = { uhi ? p1213 : o89, uhi ? p1415 : o1011, uhi ? o1213 : p89, uhi ? o1415 : p1011 }; \
    bf16x8 pb0 = __builtin_bit_cast(bf16x8, w0);                             \
    bf16x8 pb1 = __builtin_bit_cast(bf16x8, w1);                             \
    __builtin_amdgcn_s_setprio(1);                                           \
    oacc[0] = __builtin_amdgcn_mfma_f32_32x32x16_bf16(vf[0], pb0, oacc[0], 0, 0, 0); \
    oacc[0] = __builtin_amdgcn_mfma_f32_32x32x16_bf16(vf[1], pb1, oacc[0], 0, 0, 0); \
    oacc[1] = __builtin_amdgcn_mfma_f32_32x32x16_bf16(vf[2], pb0, oacc[1], 0, 0, 0); \
    oacc[1] = __builtin_amdgcn_mfma_f32_32x32x16_bf16(vf[3], pb1, oacc[1], 0, 0, 0); \
    __builtin_amdgcn_s_setprio(0);                                           \
  }

__global__ __launch_bounds__(256, 3) void attn_kernel(
    const bf16_t* __restrict__ qkv,   // [4096][3072] (q at hcol)
    const bf16_t* __restrict__ kfs, const bf16_t* __restrict__ vfs,  // self packed
    const bf16_t* __restrict__ kfc, const bf16_t* __restrict__ vfc,  // cross packed
    bf16_t* __restrict__ obuf) {      // [8192][1024]
  __shared__ __align__(16) float sO[4][34][64];  // 34816 B; first 4KB reused as swb

  const int tid = threadIdx.x;
  const int w = tid >> 6, l = tid & 63;
  const int ql = l & 31;
  const bool uhi = l >= 32;
  const int kv4 = uhi ? 4 : 0;
  const int hi8 = uhi ? 8 : 0;

  const int bid = blockIdx.x;
  const bool is_self = bid < 2048;
  int qt, bh, nt;
  if (is_self) {  // heaviest q-tiles (qt=31) dispatch first
    qt = 31 - (bid >> 6);
    bh = bid & 63;
    nt = qt + 1;
  } else {
    int cb = bid - 2048;
    qt = cb >> 6;
    bh = cb & 63;
    nt = 8;
  }
  const int b = bh >> 4, h = bh & 15;
  const int hcol = h * 64;
  const int q0 = qt * 32;

  const bf16_t* kba; const bf16_t* vba; int ooff;
  if (is_self) {
    kba = kfs + (size_t)bh * 32 * 2048; vba = vfs + (size_t)bh * 32 * 2048; ooff = 0;
  } else {
    kba = kfc + (size_t)bh * 8 * 2048;  vba = vfc + (size_t)bh * 8 * 2048;  ooff = 1024;
  }

  // Q fragments (B-operand): lane holds col q = ql, k = hd = ks*16 + hi8 + j
  const bf16_t* qrow = qkv + (size_t)(b * 1024 + q0 + ql) * 3072 + hcol + hi8;
  bf16x8 qf[4];
#pragma unroll
  for (int ks = 0; ks < 4; ++ks) qf[ks] = *(const bf16x8*)(qrow + ks * 16);

  float mcur = -1e30f, lcur = 0.f;  // RAW (pre-scale) units
  f32x16 sa = {};
  f32x16 oacc[2] = {};
  bf16x8 kf[4], vfA[4], vfB[4];

  int t = w;
  if (t < nt) { LOADK(t); LOADV(vfA, t); QKT(); }
  while (t < nt) {
    {  // phase A: current V in vfA
      const int nxt = t + 4;
      if (nxt < nt) { LOADK(nxt); LOADV(vfB, nxt); }
      SMPV(vfA, t);
      if (nxt < nt) QKT();
      t = nxt;
    }
    if (t >= nt) break;
    {  // phase B: current V in vfB
      const int nxt = t + 4;
      if (nxt < nt) { LOADK(nxt); LOADV(vfA, nxt); }
      SMPV(vfB, t);
      if (nxt < nt) QKT();
      t = nxt;
    }
  }

  // ---- dump partials ----
#pragma unroll
  for (int mb = 0; mb < 2; ++mb)
#pragma unroll
    for (int r = 0; r < 16; ++r)
      sO[w][mb * 16 + r][l] = oacc[mb][r];
  if (!uhi) { sO[w][32][ql] = mcur; sO[w][33][ql] = lcur; }
  __syncthreads();

  // ---- distributed merge: wave w handles O^T rows j = w*8 .. w*8+7 ----
  float m0 = sO[0][32][ql], m1 = sO[1][32][ql], m2 = sO[2][32][ql], m3 = sO[3][32][ql];
  float MM = fmaxf(fmaxf(m0, m1), fmaxf(m2, m3));
  float s0 = FEXP2((m0 - MM) * EXP2C), s1 = FEXP2((m1 - MM) * EXP2C);
  float s2 = FEXP2((m2 - MM) * EXP2C), s3 = FEXP2((m3 - MM) * EXP2C);
  float LL = sO[0][33][ql] * s0 + sO[1][33][ql] * s1 +
             sO[2][33][ql] * s2 + sO[3][33][ql] * s3;
  const float rl = 1.0f / LL;
  float mg[8];
#pragma unroll
  for (int jj = 0; jj < 8; ++jj) {
    int j = w * 8 + jj;
    mg[jj] = (sO[0][j][l] * s0 + sO[1][j][l] * s1 +
              sO[2][j][l] * s2 + sO[3][j][l] * s3) * rl;
  }
  __syncthreads();  // all sO reads done; safe to alias swb onto sO
  char* swb = (char*)&sO[0][0][0];
#pragma unroll
  for (int jj = 0; jj < 8; jj += 2) {
    int j0 = w * 8 + jj;
    int mb = j0 >> 4, r = j0 & 15, r2 = r >> 1;
    int hdb = (r2 & 1) * 2 + 8 * (r2 >> 1) + kv4 + mb * 32;
    int off = (ql * 128 + hdb * 2) ^ ((ql & 7) << 4);
    *(unsigned*)(swb + off) = pkbf(mg[jj], mg[jj + 1]);
  }
  __syncthreads();
  // ---- cooperative coalesced store: 256 threads x 16B = 32q x 64hd ----
  {
    const int orow = b * 2048 + ooff + q0;
    int q = tid >> 3, ch = tid & 7;
    int off = (q * 128 + ch * 16) ^ ((q & 7) << 4);
    uint4 d = *(uint4*)(swb + off);
    *(uint4*)&obuf[(size_t)(orow + q) * 1024 + hcol + ch * 8] = d;
  }
}

// ---------------------------------------------------------------------------
extern "C" void kernel_launch(void* const* d_in, const int* in_sizes, int n_in,
                              void* d_out, int out_size, void* d_ws, size_t ws_size,
                              hipStream_t stream) {
  (void)in_sizes; (void)n_in; (void)out_size; (void)ws_size;
  const float* x   = (const float*)d_in[0];
  const float* pkg = (const float*)d_in[1];
  const float* Wc  = (const float*)d_in[2];
  const float* bc  = (const float*)d_in[3];
  const float* Wk  = (const float*)d_in[4];
  const float* bk  = (const float*)d_in[5];
  const float* Wp  = (const float*)d_in[6];
  const float* bp  = (const float*)d_in[7];
  float* out = (float*)d_out;

  char* ws = (char*)d_ws;
  const size_t MB = 1u << 20;
  bf16_t* xb   = (bf16_t*)(ws + 0 * MB);   // [4096][1024]   8 MB (dead after qkv GEMM)
  bf16_t* pkb  = (bf16_t*)(ws + 8 * MB);   // [1024][1024]   2 MB (dead after kkv GEMM)
  bf16_t* Wct  = (bf16_t*)(ws + 10 * MB);  // [3072][1024]   6 MB (dead after qkv GEMM)
  bf16_t* Wkt  = (bf16_t*)(ws + 16 * MB);  // [2048][1024]   4 MB
  bf16_t* Wpt  = (bf16_t*)(ws + 20 * MB);  // [1024][1024]   2 MB
  bf16_t* kkvb = (bf16_t*)(ws + 22 * MB);  // [1024][2048]   4 MB
  bf16_t* abuf = (bf16_t*)(ws + 26 * MB);  // [8192][1024]  16 MB  (ws total 42 MB)
  bf16_t* vfs  = (bf16_t*)(ws + 0 * MB);   // packed self V^T frags  8 MB (reuses xb)
  bf16_t* kfc  = (bf16_t*)(ws + 8 * MB);   // packed cross K frags   2 MB (reuses pkb)
  bf16_t* vfc  = (bf16_t*)(ws + 10 * MB);  // packed cross V^T frags 2 MB (reuses Wct)
  // d_out double-duty: qkv intermediate + packed self K frags
  bf16_t* qkvb = (bf16_t*)d_out;                      // [4096][3072] 24 MB
  bf16_t* kfs  = (bf16_t*)((char*)d_out + 24 * MB);   // packed self K frags 8 MB

  cvt_kernel<<<4096, 256, 0, stream>>>(x, xb, 4096 * 1024 / 4);
  cvt_kernel<<<1024, 256, 0, stream>>>(pkg, pkb, 1024 * 1024 / 4);
  tcvt_kernel<<<dim3(3072 / 32, 1024 / 32), 256, 0, stream>>>(Wc, Wct, 1024, 3072);
  tcvt_kernel<<<dim3(2048 / 32, 1024 / 32), 256, 0, stream>>>(Wk, Wkt, 1024, 2048);
  tcvt_kernel<<<dim3(1024 / 32, 1024 / 32), 256, 0, stream>>>(Wp, Wpt, 1024, 1024);

  gemm_bt_kernel<0><<<dim3(24, 32), 256, 0, stream>>>(xb, Wct, bc, qkvb, 4096, 3072, 1024);
  gemm_bt_kernel<0><<<dim3(16, 8), 256, 0, stream>>>(pkb, Wkt, bk, kkvb, 1024, 2048, 1024);

  // fragment-order packing (K and V^T), self then cross
  pack_kernel<<<dim3(32, 64), 256, 0, stream>>>(qkvb, kfs, vfs, 1024, 3072, 1024, 2048);
  pack_kernel<<<dim3(8, 64), 256, 0, stream>>>(kkvb, kfc, vfc, 256, 2048, 0, 1024);

  attn_kernel<<<dim3(4096), 256, 0, stream>>>(qkvb, kfs, vfs, kfc, vfc, abuf);

  gemm_bt_kernel<1><<<dim3(8, 64), 256, 0, stream>>>(abuf, Wpt, bp, out, 8192, 1024, 1024);
}

// Round 8
// 146.834 us; speedup vs baseline: 1.1738x; 1.0678x over previous
//
#include <hip/hip_runtime.h>
#include <hip/hip_bf16.h>

typedef __bf16 bf16_t;
typedef bf16_t bf16x8 __attribute__((ext_vector_type(8)));
typedef bf16_t bf16x4 __attribute__((ext_vector_type(4)));
typedef float f32x4 __attribute__((ext_vector_type(4)));
typedef float f32x16 __attribute__((ext_vector_type(16)));

#define EXP2C 0.1803368867f  // 0.125 * log2(e)
#define FEXP2(x) __builtin_amdgcn_exp2f(x)  // v_exp_f32 (base-2)

// async global->LDS, 16B per lane (dest must be wave-uniform base + lane*16)
__device__ __forceinline__ void gload16(const void* g, void* l) {
  __builtin_amdgcn_global_load_lds(
      (const __attribute__((address_space(1))) void*)g,
      (__attribute__((address_space(3))) void*)l, 16, 0, 0);
}

__device__ __forceinline__ unsigned pkbf(float lo, float hi) {
  unsigned short a = __builtin_bit_cast(unsigned short, (bf16_t)lo);
  unsigned short b = __builtin_bit_cast(unsigned short, (bf16_t)hi);
  return (unsigned)a | ((unsigned)b << 16);
}

// v_permlane32_swap_b32: swaps a.hi(lanes32-63) with b.lo(lanes0-31).
// After: a = [a.lo | b.lo], b = [a.hi | b.hi].
__device__ __forceinline__ void plswap(unsigned& a, unsigned& b) {
#if __has_builtin(__builtin_amdgcn_permlane32_swap)
  auto r = __builtin_amdgcn_permlane32_swap(a, b, false, false);
  a = r[0]; b = r[1];
#else
  asm("v_permlane32_swap_b32 %0, %1" : "+v"(a), "+v"(b));
#endif
}
__device__ __forceinline__ float xmax32(float x) {  // max(own, lane^32)
  unsigned a = __builtin_bit_cast(unsigned, x), b = a;
  plswap(a, b);  // a=[lo|lo], b=[hi|hi] -> fmax covers both halves in all lanes
  return fmaxf(__builtin_bit_cast(float, a), __builtin_bit_cast(float, b));
}
__device__ __forceinline__ float xsum32(float x) {  // own + lane^32
  unsigned a = __builtin_bit_cast(unsigned, x), b = a;
  plswap(a, b);
  return __builtin_bit_cast(float, a) + __builtin_bit_cast(float, b);
}

// ---------------------------------------------------------------------------
// fused convert f32 -> bf16 for x and pred_kg
// ---------------------------------------------------------------------------
__global__ __launch_bounds__(256) void cvt2_kernel(const float* __restrict__ a,
                                                   bf16_t* __restrict__ ao, int na4,
                                                   const float* __restrict__ b,
                                                   bf16_t* __restrict__ bo, int nb4) {
  int i = blockIdx.x * 256 + threadIdx.x;
  const float* src; bf16_t* dst;
  if (i < na4) { src = a; dst = ao; }
  else { i -= na4; if (i >= nb4) return; src = b; dst = bo; }
  float4 v = reinterpret_cast<const float4*>(src)[i];
  bf16x4 o = { (bf16_t)v.x, (bf16_t)v.y, (bf16_t)v.z, (bf16_t)v.w };
  reinterpret_cast<bf16x4*>(dst)[i] = o;
}

// ---------------------------------------------------------------------------
// fused transpose+convert for Wc (N=3072), Wk (2048), Wp (1024); K=1024 all
// ---------------------------------------------------------------------------
__global__ __launch_bounds__(256) void tcvt3_kernel(
    const float* __restrict__ W0, bf16_t* __restrict__ T0,
    const float* __restrict__ W1, bf16_t* __restrict__ T1,
    const float* __restrict__ W2, bf16_t* __restrict__ T2) {
  __shared__ float tile[32][33];
  int x = blockIdx.x;
  const float* W; bf16_t* T; int N;
  if (x < 96) { W = W0; T = T0; N = 3072; }
  else if (x < 160) { W = W1; T = T1; N = 2048; x -= 96; }
  else { W = W2; T = T2; N = 1024; x -= 160; }
  const int K = 1024;
  int tx = threadIdx.x & 31, ty = threadIdx.x >> 5;
  int n0 = x * 32, k0 = blockIdx.y * 32;
#pragma unroll
  for (int i = 0; i < 4; ++i)
    tile[ty + i * 8][tx] = W[(size_t)(k0 + ty + i * 8) * N + n0 + tx];
  __syncthreads();
#pragma unroll
  for (int i = 0; i < 4; ++i)
    T[(size_t)(n0 + ty + i * 8) * K + k0 + tx] = (bf16_t)tile[tx][ty + i * 8];
}

// ---------------------------------------------------------------------------
// fused pack (self + cross): K and V of one (bh, kv-tile) -> MFMA frag order
// ---------------------------------------------------------------------------
__global__ __launch_bounds__(256) void pack2_kernel(
    const bf16_t* __restrict__ src0, bf16_t* __restrict__ kd0, bf16_t* __restrict__ vd0,
    const bf16_t* __restrict__ src1, bf16_t* __restrict__ kd1, bf16_t* __restrict__ vd1) {
  __shared__ bf16_t vt[32][72];
  const int tid = threadIdx.x;
  int x = blockIdx.x;
  const int bh = blockIdx.y;
  const bf16_t* src; bf16_t *kd, *vd; int R, stride, kcol, vcol, NT, t;
  if (x < 32) { src = src0; kd = kd0; vd = vd0; R = 1024; stride = 3072; kcol = 1024; vcol = 2048; NT = 32; t = x; }
  else        { src = src1; kd = kd1; vd = vd1; R = 256;  stride = 2048; kcol = 0;    vcol = 1024; NT = 8;  t = x - 32; }
  const int b = bh >> 4, h = bh & 15;
  const size_t srow = (size_t)b * R + t * 32;
  const size_t obase = ((size_t)bh * NT + t) * 2048;
  {  // V tile -> LDS
    int r = tid >> 3, c = tid & 7;
    bf16x8 d = *(const bf16x8*)&src[(srow + r) * stride + vcol + h * 64 + c * 8];
    *(bf16x8*)&vt[r][c * 8] = d;
  }
  {  // K fragments: direct global->global
    int ks = tid >> 6, l = tid & 63;
    int hi8 = (l >> 5) * 8;
    bf16x8 d = *(const bf16x8*)&src[(srow + (l & 31)) * stride + kcol + h * 64 + ks * 16 + hi8];
    *(bf16x8*)&kd[obase + ks * 512 + l * 8] = d;
  }
  __syncthreads();
  {  // V^T fragments from LDS
    int dd = tid >> 6, l = tid & 63;
    int mb = dd >> 1, ks = dd & 1;
    int hd = mb * 32 + (l & 31);
    int kvr = ks * 16 + (l >> 5) * 8;
    bf16x8 o;
#pragma unroll
    for (int j = 0; j < 8; ++j) o[j] = vt[kvr + j][hd];
    *(bf16x8*)&vd[obase + dd * 512 + l * 8] = o;
  }
}

// ---------------------------------------------------------------------------
// GEMM body: C[128x128 tile] = A @ Bt^T + bias. BK=32, 4 waves,
// 4x4 mfma_f32_16x16x32_bf16, 2-phase double-buffered gload_lds staging.
// ---------------------------------------------------------------------------
template <int OUTF32>
__device__ __forceinline__ void gemm_body(
    bf16_t* sA, bf16_t* sB,  // [2][128*32] each
    const bf16_t* __restrict__ A, const bf16_t* __restrict__ Bt,
    const float* __restrict__ bias, void* __restrict__ Cout,
    int N, int K, int bx, int by) {
  const int tid = threadIdx.x;
  const int l = tid & 63, w = tid >> 6;
  const int lr = l & 15, lg = l >> 4;
  const int m0 = by * 128, n0 = bx * 128;
  const int wr = (w >> 1) * 64, wc = (w & 1) * 64;

  const int i0 = tid, i1 = tid + 256;
  const bf16_t* ga0 = A + (size_t)(m0 + (i0 >> 2)) * K + (i0 & 3) * 8;
  const bf16_t* ga1 = A + (size_t)(m0 + (i1 >> 2)) * K + (i1 & 3) * 8;
  const bf16_t* gb0 = Bt + (size_t)(n0 + (i0 >> 2)) * K + (i0 & 3) * 8;
  const bf16_t* gb1 = Bt + (size_t)(n0 + (i1 >> 2)) * K + (i1 & 3) * 8;

  f32x4 acc[4][4] = {};
  const int nk = K >> 5;
  const int HB = 128 * 32;

  gload16(ga0, &sA[i0 * 8]);
  gload16(ga1, &sA[i1 * 8]);
  gload16(gb0, &sB[i0 * 8]);
  gload16(gb1, &sB[i1 * 8]);
  __syncthreads();

  int cur = 0;
  for (int kt = 0; kt < nk; ++kt) {
    if (kt + 1 < nk) {
      const int ko = (kt + 1) * 32;
      const int nb = (cur ^ 1) * HB;
      gload16(ga0 + ko, &sA[nb + i0 * 8]);
      gload16(ga1 + ko, &sA[nb + i1 * 8]);
      gload16(gb0 + ko, &sB[nb + i0 * 8]);
      gload16(gb1 + ko, &sB[nb + i1 * 8]);
    }
    bf16x8 af[4], bv[4];
#pragma unroll
    for (int mf = 0; mf < 4; ++mf)
      af[mf] = *(const bf16x8*)&sA[cur * HB + (wr + mf * 16 + lr) * 32 + lg * 8];
#pragma unroll
    for (int nf = 0; nf < 4; ++nf)
      bv[nf] = *(const bf16x8*)&sB[cur * HB + (wc + nf * 16 + lr) * 32 + lg * 8];
#pragma unroll
    for (int mf = 0; mf < 4; ++mf)
#pragma unroll
      for (int nf = 0; nf < 4; ++nf)
        acc[mf][nf] = __builtin_amdgcn_mfma_f32_16x16x32_bf16(af[mf], bv[nf], acc[mf][nf], 0, 0, 0);
    __syncthreads();
    cur ^= 1;
  }

#pragma unroll
  for (int mf = 0; mf < 4; ++mf) {
#pragma unroll
    for (int nf = 0; nf < 4; ++nf) {
      int col = n0 + wc + nf * 16 + lr;
      float bb = bias[col];
      int rowb = m0 + wr + mf * 16 + lg * 4;
#pragma unroll
      for (int r = 0; r < 4; ++r) {
        float v = acc[mf][nf][r] + bb;
        if constexpr (OUTF32)
          ((float*)Cout)[(size_t)(rowb + r) * N + col] = v;
        else
          ((bf16_t*)Cout)[(size_t)(rowb + r) * N + col] = (bf16_t)v;
      }
    }
  }
}

// fused qkv + kkv GEMM (one launch, block-range dispatch)
__global__ __launch_bounds__(256) void gemm2_kernel(
    const bf16_t* __restrict__ A0, const bf16_t* __restrict__ B0,
    const float* __restrict__ bi0, bf16_t* __restrict__ C0, int N0, int nbx0, int split,
    const bf16_t* __restrict__ A1, const bf16_t* __restrict__ B1,
    const float* __restrict__ bi1, bf16_t* __restrict__ C1, int N1, int nbx1) {
  __shared__ __align__(16) bf16_t sA[2][128 * 32];
  __shared__ __align__(16) bf16_t sB[2][128 * 32];
  int bid = blockIdx.x;
  if (bid < split)
    gemm_body<0>(&sA[0][0], &sB[0][0], A0, B0, bi0, C0, N0, 1024, bid % nbx0, bid / nbx0);
  else {
    int r = bid - split;
    gemm_body<0>(&sA[0][0], &sB[0][0], A1, B1, bi1, C1, N1, 1024, r % nbx1, r / nbx1);
  }
}

// proj GEMM (fp32 out)
__global__ __launch_bounds__(256) void gemm_proj_kernel(
    const bf16_t* __restrict__ A, const bf16_t* __restrict__ Bt,
    const float* __restrict__ bias, float* __restrict__ Cout, int N, int K) {
  __shared__ __align__(16) bf16_t sA[2][128 * 32];
  __shared__ __align__(16) bf16_t sB[2][128 * 32];
  gemm_body<1>(&sA[0][0], &sB[0][0], A, Bt, bias, Cout, N, K, blockIdx.x, blockIdx.y);
}

// ---------------------------------------------------------------------------
// Flash attention, intra-block split-KV, fragment-packed K/V, permlane
// softmax exchange (T12). Distributed 4-wave merge epilogue.
// ---------------------------------------------------------------------------
#define LOADK(t)                                                             \
  {                                                                          \
    _Pragma("unroll") for (int c = 0; c < 4; ++c)                            \
        kf[c] = *(const bf16x8*)(kba + (size_t)(t) * 2048 + c * 512 + l * 8);\
  }
#define LOADV(vf, t)                                                         \
  {                                                                          \
    _Pragma("unroll") for (int c = 0; c < 4; ++c)                            \
        vf[c] = *(const bf16x8*)(vba + (size_t)(t) * 2048 + c * 512 + l * 8);\
  }
#define QKT()                                                                \
  {                                                                          \
    sa = (f32x16){};                                                         \
    __builtin_amdgcn_s_setprio(1);                                           \
    _Pragma("unroll") for (int ks = 0; ks < 4; ++ks)                         \
        sa = __builtin_amdgcn_mfma_f32_32x32x16_bf16(kf[ks], qf[ks], sa, 0, 0, 0); \
    __builtin_amdgcn_s_setprio(0);                                           \
  }
#define SMPV(vf, tcur)                                                       \
  {                                                                          \
    float sv[16];                                                            \
    const bool mt = is_self && ((tcur) == qt);                               \
    _Pragma("unroll") for (int r = 0; r < 16; ++r) {                         \
      float v = sa[r];                                                       \
      if (mt) {                                                              \
        int kvr = (r & 3) + 8 * (r >> 2) + kv4;                              \
        v = (kvr > ql) ? -1e30f : v;                                         \
      }                                                                      \
      sv[r] = v;                                                             \
    }                                                                        \
    float tm = fmaxf(                                                        \
        fmaxf(fmaxf(fmaxf(sv[0], sv[1]), fmaxf(sv[2], sv[3])),               \
              fmaxf(fmaxf(sv[4], sv[5]), fmaxf(sv[6], sv[7]))),              \
        fmaxf(fmaxf(fmaxf(sv[8], sv[9]), fmaxf(sv[10], sv[11])),             \
              fmaxf(fmaxf(sv[12], sv[13]), fmaxf(sv[14], sv[15]))));         \
    tm = xmax32(tm);                                                         \
    if (!__all(tm <= mcur + 64.f)) {                                         \
      float mn = fmaxf(mcur, tm);                                            \
      float sc = FEXP2((mcur - mn) * EXP2C);                                 \
      mcur = mn;                                                             \
      lcur *= sc;                                                            \
      _Pragma("unroll") for (int mb = 0; mb < 2; ++mb)                       \
          _Pragma("unroll") for (int r = 0; r < 16; ++r) oacc[mb][r] *= sc;  \
    }                                                                        \
    const float hm = mcur * EXP2C;                                           \
    float pf[16];                                                            \
    _Pragma("unroll") for (int r = 0; r < 16; ++r)                           \
        pf[r] = FEXP2(__builtin_fmaf(sv[r], EXP2C, -hm));                    \
    float ps = (((pf[0] + pf[1]) + (pf[2] + pf[3])) +                        \
                ((pf[4] + pf[5]) + (pf[6] + pf[7]))) +                       \
               (((pf[8] + pf[9]) + (pf[10] + pf[11])) +                      \
                ((pf[12] + pf[13]) + (pf[14] + pf[15])));                    \
    ps = xsum32(ps);                                                         \
    lcur += ps;                                                              \
    unsigned o01 = pkbf(pf[0], pf[1]), o23 = pkbf(pf[2], pf[3]);             \
    unsigned o45 = pkbf(pf[4], pf[5]), o67 = pkbf(pf[6], pf[7]);             \
    unsigned o89 = pkbf(pf[8], pf[9]), o1011 = pkbf(pf[10], pf[11]);         \
    unsigned o1213 = pkbf(pf[12], pf[13]), o1415 = pkbf(pf[14], pf[15]);     \
    plswap(o01, o45); plswap(o23, o67);                                      \
    plswap(o89, o1213); plswap(o1011, o1415);                                \
    uint4 w0 = { o01, o23, o45, o67 };                                       \
    uint4 w1 = { o89, o1011, o1213, o1415 };                                 \
    bf16x8 pb0 = __builtin_bit_cast(bf16x8, w0);                             \
    bf16x8 pb1 = __builtin_bit_cast(bf16x8, w1);                             \
    __builtin_amdgcn_s_setprio(1);                                           \
    oacc[0] = __builtin_amdgcn_mfma_f32_32x32x16_bf16(vf[0], pb0, oacc[0], 0, 0, 0); \
    oacc[0] = __builtin_amdgcn_mfma_f32_32x32x16_bf16(vf[1], pb1, oacc[0], 0, 0, 0); \
    oacc[1] = __builtin_amdgcn_mfma_f32_32x32x16_bf16(vf[2], pb0, oacc[1], 0, 0, 0); \
    oacc[1] = __builtin_amdgcn_mfma_f32_32x32x16_bf16(vf[3], pb1, oacc[1], 0, 0, 0); \
    __builtin_amdgcn_s_setprio(0);                                           \
  }

__global__ __launch_bounds__(256, 3) void attn_kernel(
    const bf16_t* __restrict__ qkv,   // [4096][3072] (q at hcol)
    const bf16_t* __restrict__ kfs, const bf16_t* __restrict__ vfs,  // self packed
    const bf16_t* __restrict__ kfc, const bf16_t* __restrict__ vfc,  // cross packed
    bf16_t* __restrict__ obuf) {      // [8192][1024]
  __shared__ __align__(16) float sO[4][34][64];  // 34816 B; first 4KB reused as swb

  const int tid = threadIdx.x;
  const int w = tid >> 6, l = tid & 63;
  const int ql = l & 31;
  const bool uhi = l >= 32;
  const int kv4 = uhi ? 4 : 0;
  const int hi8 = uhi ? 8 : 0;

  const int bid = blockIdx.x;
  const bool is_self = bid < 2048;
  int qt, bh, nt;
  if (is_self) {  // heaviest q-tiles (qt=31) dispatch first
    qt = 31 - (bid >> 6);
    bh = bid & 63;
    nt = qt + 1;
  } else {
    int cb = bid - 2048;
    qt = cb >> 6;
    bh = cb & 63;
    nt = 8;
  }
  const int b = bh >> 4, h = bh & 15;
  const int hcol = h * 64;
  const int q0 = qt * 32;

  const bf16_t* kba; const bf16_t* vba; int ooff;
  if (is_self) {
    kba = kfs + (size_t)bh * 32 * 2048; vba = vfs + (size_t)bh * 32 * 2048; ooff = 0;
  } else {
    kba = kfc + (size_t)bh * 8 * 2048;  vba = vfc + (size_t)bh * 8 * 2048;  ooff = 1024;
  }

  // Q fragments (B-operand): lane holds col q = ql, k = hd = ks*16 + hi8 + j
  const bf16_t* qrow = qkv + (size_t)(b * 1024 + q0 + ql) * 3072 + hcol + hi8;
  bf16x8 qf[4];
#pragma unroll
  for (int ks = 0; ks < 4; ++ks) qf[ks] = *(const bf16x8*)(qrow + ks * 16);

  float mcur = -1e30f, lcur = 0.f;  // RAW (pre-scale) units
  f32x16 sa = {};
  f32x16 oacc[2] = {};
  bf16x8 kf[4], vfA[4], vfB[4];

  int t = w;
  if (t < nt) { LOADK(t); LOADV(vfA, t); QKT(); }
  while (t < nt) {
    {  // phase A: current V in vfA
      const int nxt = t + 4;
      if (nxt < nt) { LOADK(nxt); LOADV(vfB, nxt); }
      SMPV(vfA, t);
      if (nxt < nt) QKT();
      t = nxt;
    }
    if (t >= nt) break;
    {  // phase B: current V in vfB
      const int nxt = t + 4;
      if (nxt < nt) { LOADK(nxt); LOADV(vfA, nxt); }
      SMPV(vfB, t);
      if (nxt < nt) QKT();
      t = nxt;
    }
  }

  // ---- dump partials ----
#pragma unroll
  for (int mb = 0; mb < 2; ++mb)
#pragma unroll
    for (int r = 0; r < 16; ++r)
      sO[w][mb * 16 + r][l] = oacc[mb][r];
  if (!uhi) { sO[w][32][ql] = mcur; sO[w][33][ql] = lcur; }
  __syncthreads();

  // ---- distributed merge: wave w handles O^T rows j = w*8 .. w*8+7 ----
  float m0 = sO[0][32][ql], m1 = sO[1][32][ql], m2 = sO[2][32][ql], m3 = sO[3][32][ql];
  float MM = fmaxf(fmaxf(m0, m1), fmaxf(m2, m3));
  float s0 = FEXP2((m0 - MM) * EXP2C), s1 = FEXP2((m1 - MM) * EXP2C);
  float s2 = FEXP2((m2 - MM) * EXP2C), s3 = FEXP2((m3 - MM) * EXP2C);
  float LL = sO[0][33][ql] * s0 + sO[1][33][ql] * s1 +
             sO[2][33][ql] * s2 + sO[3][33][ql] * s3;
  const float rl = 1.0f / LL;
  float mg[8];
#pragma unroll
  for (int jj = 0; jj < 8; ++jj) {
    int j = w * 8 + jj;
    mg[jj] = (sO[0][j][l] * s0 + sO[1][j][l] * s1 +
              sO[2][j][l] * s2 + sO[3][j][l] * s3) * rl;
  }
  __syncthreads();  // all sO reads done; safe to alias swb onto sO
  char* swb = (char*)&sO[0][0][0];
#pragma unroll
  for (int jj = 0; jj < 8; jj += 2) {
    int j0 = w * 8 + jj;
    int mb = j0 >> 4, r = j0 & 15, r2 = r >> 1;
    int hdb = (r2 & 1) * 2 + 8 * (r2 >> 1) + kv4 + mb * 32;
    int off = (ql * 128 + hdb * 2) ^ ((ql & 7) << 4);
    *(unsigned*)(swb + off) = pkbf(mg[jj], mg[jj + 1]);
  }
  __syncthreads();
  // ---- cooperative coalesced store: 256 threads x 16B = 32q x 64hd ----
  {
    const int orow = b * 2048 + ooff + q0;
    int q = tid >> 3, ch = tid & 7;
    int off = (q * 128 + ch * 16) ^ ((q & 7) << 4);
    uint4 d = *(uint4*)(swb + off);
    *(uint4*)&obuf[(size_t)(orow + q) * 1024 + hcol + ch * 8] = d;
  }
}

// ---------------------------------------------------------------------------
extern "C" void kernel_launch(void* const* d_in, const int* in_sizes, int n_in,
                              void* d_out, int out_size, void* d_ws, size_t ws_size,
                              hipStream_t stream) {
  (void)in_sizes; (void)n_in; (void)out_size; (void)ws_size;
  const float* x   = (const float*)d_in[0];
  const float* pkg = (const float*)d_in[1];
  const float* Wc  = (const float*)d_in[2];
  const float* bc  = (const float*)d_in[3];
  const float* Wk  = (const float*)d_in[4];
  const float* bk  = (const float*)d_in[5];
  const float* Wp  = (const float*)d_in[6];
  const float* bp  = (const float*)d_in[7];
  float* out = (float*)d_out;

  char* ws = (char*)d_ws;
  const size_t MB = 1u << 20;
  bf16_t* xb   = (bf16_t*)(ws + 0 * MB);   // [4096][1024]   8 MB (dead after qkv GEMM)
  bf16_t* pkb  = (bf16_t*)(ws + 8 * MB);   // [1024][1024]   2 MB (dead after kkv GEMM)
  bf16_t* Wct  = (bf16_t*)(ws + 10 * MB);  // [3072][1024]   6 MB (dead after qkv GEMM)
  bf16_t* Wkt  = (bf16_t*)(ws + 16 * MB);  // [2048][1024]   4 MB
  bf16_t* Wpt  = (bf16_t*)(ws + 20 * MB);  // [1024][1024]   2 MB
  bf16_t* kkvb = (bf16_t*)(ws + 22 * MB);  // [1024][2048]   4 MB
  bf16_t* abuf = (bf16_t*)(ws + 26 * MB);  // [8192][1024]  16 MB  (ws total 42 MB)
  bf16_t* vfs  = (bf16_t*)(ws + 0 * MB);   // packed self V^T frags  8 MB (reuses xb)
  bf16_t* kfc  = (bf16_t*)(ws + 8 * MB);   // packed cross K frags   2 MB (reuses pkb)
  bf16_t* vfc  = (bf16_t*)(ws + 10 * MB);  // packed cross V^T frags 2 MB (reuses Wct)
  // d_out double-duty: qkv intermediate + packed self K frags
  bf16_t* qkvb = (bf16_t*)d_out;                      // [4096][3072] 24 MB
  bf16_t* kfs  = (bf16_t*)((char*)d_out + 24 * MB);   // packed self K frags 8 MB

  // 1: convert x + pred_kg
  cvt2_kernel<<<5120, 256, 0, stream>>>(x, xb, 1048576, pkg, pkb, 262144);
  // 2: transpose-convert all three weights
  tcvt3_kernel<<<dim3(192, 32), 256, 0, stream>>>(Wc, Wct, Wk, Wkt, Wp, Wpt);
  // 3: qkv GEMM (24x32=768 blocks) + kkv GEMM (16x8=128 blocks)
  gemm2_kernel<<<896, 256, 0, stream>>>(xb, Wct, bc, qkvb, 3072, 24, 768,
                                        pkb, Wkt, bk, kkvb, 2048, 16);
  // 4: fragment packing (self 32 tiles + cross 8 tiles) x 64 bh
  pack2_kernel<<<dim3(40, 64), 256, 0, stream>>>(qkvb, kfs, vfs, kkvb, kfc, vfc);
  // 5: attention (both branches)
  attn_kernel<<<4096, 256, 0, stream>>>(qkvb, kfs, vfs, kfc, vfc, abuf);
  // 6: output projection
  gemm_proj_kernel<<<dim3(8, 64), 256, 0, stream>>>(abuf, Wpt, bp, out, 1024, 1024);
}

// Round 9
// 128.028 us; speedup vs baseline: 1.3462x; 1.1469x over previous
//
#include <hip/hip_runtime.h>
#include <hip/hip_bf16.h>

typedef __bf16 bf16_t;
typedef bf16_t bf16x8 __attribute__((ext_vector_type(8)));
typedef bf16_t bf16x4 __attribute__((ext_vector_type(4)));
typedef float f32x4 __attribute__((ext_vector_type(4)));
typedef float f32x16 __attribute__((ext_vector_type(16)));

#define EXP2C 0.1803368867f  // 0.125 * log2(e)
#define FEXP2(x) __builtin_amdgcn_exp2f(x)  // v_exp_f32 (base-2)

// async global->LDS, 16B per lane (dest must be wave-uniform base + lane*16)
__device__ __forceinline__ void gload16(const void* g, void* l) {
  __builtin_amdgcn_global_load_lds(
      (const __attribute__((address_space(1))) void*)g,
      (__attribute__((address_space(3))) void*)l, 16, 0, 0);
}

__device__ __forceinline__ unsigned pkbf(float lo, float hi) {
  unsigned short a = __builtin_bit_cast(unsigned short, (bf16_t)lo);
  unsigned short b = __builtin_bit_cast(unsigned short, (bf16_t)hi);
  return (unsigned)a | ((unsigned)b << 16);
}

// v_permlane32_swap_b32: swaps a.hi(lanes32-63) with b.lo(lanes0-31).
__device__ __forceinline__ void plswap(unsigned& a, unsigned& b) {
#if __has_builtin(__builtin_amdgcn_permlane32_swap)
  auto r = __builtin_amdgcn_permlane32_swap(a, b, false, false);
  a = r[0]; b = r[1];
#else
  asm("v_permlane32_swap_b32 %0, %1" : "+v"(a), "+v"(b));
#endif
}
__device__ __forceinline__ float xmax32(float x) {
  unsigned a = __builtin_bit_cast(unsigned, x), b = a;
  plswap(a, b);
  return fmaxf(__builtin_bit_cast(float, a), __builtin_bit_cast(float, b));
}
__device__ __forceinline__ float xsum32(float x) {
  unsigned a = __builtin_bit_cast(unsigned, x), b = a;
  plswap(a, b);
  return __builtin_bit_cast(float, a) + __builtin_bit_cast(float, b);
}

// ---------------------------------------------------------------------------
// fused prep: cvt x (blocks 0..4095), cvt pred_kg (4096..5119),
// tcvt Wc/Wk/Wp (5120..11263; 192 x-tiles x 32 k-tiles)
// ---------------------------------------------------------------------------
__global__ __launch_bounds__(256) void prep_kernel(
    const float* __restrict__ x, bf16_t* __restrict__ xb,
    const float* __restrict__ pkg, bf16_t* __restrict__ pkb,
    const float* __restrict__ Wc, bf16_t* __restrict__ Wct,
    const float* __restrict__ Wk, bf16_t* __restrict__ Wkt,
    const float* __restrict__ Wp, bf16_t* __restrict__ Wpt) {
  __shared__ float tile[32][33];
  const int bid = blockIdx.x, tid = threadIdx.x;
  if (bid < 5120) {  // vector convert
    int i = bid * 256 + tid;
    const float* src; bf16_t* dst;
    if (i < 1048576) { src = x; dst = xb; }
    else { i -= 1048576; src = pkg; dst = pkb; }
    float4 v = reinterpret_cast<const float4*>(src)[i];
    bf16x4 o = { (bf16_t)v.x, (bf16_t)v.y, (bf16_t)v.z, (bf16_t)v.w };
    reinterpret_cast<bf16x4*>(dst)[i] = o;
    return;
  }
  int r = bid - 5120;
  int xx = r % 192, ky = r / 192;
  const float* W; bf16_t* T; int N;
  if (xx < 96) { W = Wc; T = Wct; N = 3072; }
  else if (xx < 160) { W = Wk; T = Wkt; N = 2048; xx -= 96; }
  else { W = Wp; T = Wpt; N = 1024; xx -= 160; }
  const int K = 1024;
  int tx = tid & 31, ty = tid >> 5;
  int n0 = xx * 32, k0 = ky * 32;
#pragma unroll
  for (int i = 0; i < 4; ++i)
    tile[ty + i * 8][tx] = W[(size_t)(k0 + ty + i * 8) * N + n0 + tx];
  __syncthreads();
#pragma unroll
  for (int i = 0; i < 4; ++i)
    T[(size_t)(n0 + ty + i * 8) * K + k0 + tx] = (bf16_t)tile[tx][ty + i * 8];
}

// ---------------------------------------------------------------------------
// fused pack (self + cross): K and V of one (bh, kv-tile) -> MFMA frag order
// ---------------------------------------------------------------------------
__global__ __launch_bounds__(256) void pack2_kernel(
    const bf16_t* __restrict__ src0, bf16_t* __restrict__ kd0, bf16_t* __restrict__ vd0,
    const bf16_t* __restrict__ src1, bf16_t* __restrict__ kd1, bf16_t* __restrict__ vd1) {
  __shared__ bf16_t vt[32][72];
  const int tid = threadIdx.x;
  int x = blockIdx.x;
  const int bh = blockIdx.y;
  const bf16_t* src; bf16_t *kd, *vd; int R, stride, kcol, vcol, NT, t;
  if (x < 32) { src = src0; kd = kd0; vd = vd0; R = 1024; stride = 3072; kcol = 1024; vcol = 2048; NT = 32; t = x; }
  else        { src = src1; kd = kd1; vd = vd1; R = 256;  stride = 2048; kcol = 0;    vcol = 1024; NT = 8;  t = x - 32; }
  const int b = bh >> 4, h = bh & 15;
  const size_t srow = (size_t)b * R + t * 32;
  const size_t obase = ((size_t)bh * NT + t) * 2048;
  {  // V tile -> LDS
    int r = tid >> 3, c = tid & 7;
    bf16x8 d = *(const bf16x8*)&src[(srow + r) * stride + vcol + h * 64 + c * 8];
    *(bf16x8*)&vt[r][c * 8] = d;
  }
  {  // K fragments: direct global->global
    int ks = tid >> 6, l = tid & 63;
    int hi8 = (l >> 5) * 8;
    bf16x8 d = *(const bf16x8*)&src[(srow + (l & 31)) * stride + kcol + h * 64 + ks * 16 + hi8];
    *(bf16x8*)&kd[obase + ks * 512 + l * 8] = d;
  }
  __syncthreads();
  {  // V^T fragments from LDS
    int dd = tid >> 6, l = tid & 63;
    int mb = dd >> 1, ks = dd & 1;
    int hd = mb * 32 + (l & 31);
    int kvr = ks * 16 + (l >> 5) * 8;
    bf16x8 o;
#pragma unroll
    for (int j = 0; j < 8; ++j) o[j] = vt[kvr + j][hd];
    *(bf16x8*)&vd[obase + dd * 512 + l * 8] = o;
  }
}

// ---------------------------------------------------------------------------
// GEMM body: 256x128 tile, BK=32, 512 threads / 8 waves (4M x 2N, each wave
// 64x64 via 4x4 mfma_f32_16x16x32_bf16). 2-phase double-buffered
// global_load_lds staging. LDS 48 KB.
// ---------------------------------------------------------------------------
template <int OUTF32>
__device__ __forceinline__ void gemm_body256(
    bf16_t* sA, bf16_t* sB,  // [2][256*32], [2][128*32]
    const bf16_t* __restrict__ A, const bf16_t* __restrict__ Bt,
    const float* __restrict__ bias, void* __restrict__ Cout,
    int N, int K, int bx, int by) {
  const int tid = threadIdx.x;
  const int l = tid & 63, w = tid >> 6;
  const int lr = l & 15, lg = l >> 4;
  const int m0 = by * 256, n0 = bx * 128;
  const int wr = (w >> 1) * 64, wc = (w & 1) * 64;

  const int iA1 = tid + 512;
  const bf16_t* ga0 = A + (size_t)(m0 + (tid >> 2)) * K + (tid & 3) * 8;
  const bf16_t* ga1 = A + (size_t)(m0 + (iA1 >> 2)) * K + (tid & 3) * 8;
  const bf16_t* gb0 = Bt + (size_t)(n0 + (tid >> 2)) * K + (tid & 3) * 8;

  f32x4 acc[4][4] = {};
  const int nk = K >> 5;
  const int HA = 256 * 32, HB = 128 * 32;

  gload16(ga0, &sA[tid * 8]);
  gload16(ga1, &sA[iA1 * 8]);
  gload16(gb0, &sB[tid * 8]);
  __syncthreads();

  int cur = 0;
  for (int kt = 0; kt < nk; ++kt) {
    if (kt + 1 < nk) {
      const int ko = (kt + 1) * 32;
      const int a = (cur ^ 1) * HA, bb = (cur ^ 1) * HB;
      gload16(ga0 + ko, &sA[a + tid * 8]);
      gload16(ga1 + ko, &sA[a + iA1 * 8]);
      gload16(gb0 + ko, &sB[bb + tid * 8]);
    }
    bf16x8 af[4], bv[4];
#pragma unroll
    for (int mf = 0; mf < 4; ++mf)
      af[mf] = *(const bf16x8*)&sA[cur * HA + (wr + mf * 16 + lr) * 32 + lg * 8];
#pragma unroll
    for (int nf = 0; nf < 4; ++nf)
      bv[nf] = *(const bf16x8*)&sB[cur * HB + (wc + nf * 16 + lr) * 32 + lg * 8];
    __builtin_amdgcn_s_setprio(1);
#pragma unroll
    for (int mf = 0; mf < 4; ++mf)
#pragma unroll
      for (int nf = 0; nf < 4; ++nf)
        acc[mf][nf] = __builtin_amdgcn_mfma_f32_16x16x32_bf16(af[mf], bv[nf], acc[mf][nf], 0, 0, 0);
    __builtin_amdgcn_s_setprio(0);
    __syncthreads();
    cur ^= 1;
  }

#pragma unroll
  for (int mf = 0; mf < 4; ++mf) {
#pragma unroll
    for (int nf = 0; nf < 4; ++nf) {
      int col = n0 + wc + nf * 16 + lr;
      float bb = bias[col];
      int rowb = m0 + wr + mf * 16 + lg * 4;
#pragma unroll
      for (int r = 0; r < 4; ++r) {
        float v = acc[mf][nf][r] + bb;
        if constexpr (OUTF32)
          ((float*)Cout)[(size_t)(rowb + r) * N + col] = v;
        else
          ((bf16_t*)Cout)[(size_t)(rowb + r) * N + col] = (bf16_t)v;
      }
    }
  }
}

// fused qkv (384 blocks: 16 by x 24 bx) + kkv (64 blocks: 4 by x 16 bx),
// XCD-swizzled (448 % 8 == 0)
__global__ __launch_bounds__(512) void gemm2_kernel(
    const bf16_t* __restrict__ A0, const bf16_t* __restrict__ B0,
    const float* __restrict__ bi0, bf16_t* __restrict__ C0,
    const bf16_t* __restrict__ A1, const bf16_t* __restrict__ B1,
    const float* __restrict__ bi1, bf16_t* __restrict__ C1) {
  __shared__ __align__(16) bf16_t sA[2][256 * 32];
  __shared__ __align__(16) bf16_t sB[2][128 * 32];
  int bid = blockIdx.x;
  int wg = (bid & 7) * 56 + (bid >> 3);  // XCD-contiguous chunks
  if (wg < 384)
    gemm_body256<0>(&sA[0][0], &sB[0][0], A0, B0, bi0, C0, 3072, 1024, wg % 24, wg / 24);
  else {
    int r = wg - 384;
    gemm_body256<0>(&sA[0][0], &sB[0][0], A1, B1, bi1, C1, 2048, 1024, r % 16, r / 16);
  }
}

// proj GEMM: 256 blocks (32 by x 8 bx), XCD-swizzled, fp32 out
__global__ __launch_bounds__(512) void gemm_proj_kernel(
    const bf16_t* __restrict__ A, const bf16_t* __restrict__ Bt,
    const float* __restrict__ bias, float* __restrict__ Cout) {
  __shared__ __align__(16) bf16_t sA[2][256 * 32];
  __shared__ __align__(16) bf16_t sB[2][128 * 32];
  int bid = blockIdx.x;
  int wg = (bid & 7) * 32 + (bid >> 3);
  gemm_body256<1>(&sA[0][0], &sB[0][0], A, Bt, bias, Cout, 1024, 1024, wg % 8, wg / 8);
}

// ---------------------------------------------------------------------------
// Flash attention, intra-block split-KV, fragment-packed K/V, permlane
// softmax exchange (T12). Distributed 4-wave merge epilogue. (unchanged R8)
// ---------------------------------------------------------------------------
#define LOADK(t)                                                             \
  {                                                                          \
    _Pragma("unroll") for (int c = 0; c < 4; ++c)                            \
        kf[c] = *(const bf16x8*)(kba + (size_t)(t) * 2048 + c * 512 + l * 8);\
  }
#define LOADV(vf, t)                                                         \
  {                                                                          \
    _Pragma("unroll") for (int c = 0; c < 4; ++c)                            \
        vf[c] = *(const bf16x8*)(vba + (size_t)(t) * 2048 + c * 512 + l * 8);\
  }
#define QKT()                                                                \
  {                                                                          \
    sa = (f32x16){};                                                         \
    __builtin_amdgcn_s_setprio(1);                                           \
    _Pragma("unroll") for (int ks = 0; ks < 4; ++ks)                         \
        sa = __builtin_amdgcn_mfma_f32_32x32x16_bf16(kf[ks], qf[ks], sa, 0, 0, 0); \
    __builtin_amdgcn_s_setprio(0);                                           \
  }
#define SMPV(vf, tcur)                                                       \
  {                                                                          \
    float sv[16];                                                            \
    const bool mt = is_self && ((tcur) == qt);                               \
    _Pragma("unroll") for (int r = 0; r < 16; ++r) {                         \
      float v = sa[r];                                                       \
      if (mt) {                                                              \
        int kvr = (r & 3) + 8 * (r >> 2) + kv4;                              \
        v = (kvr > ql) ? -1e30f : v;                                         \
      }                                                                      \
      sv[r] = v;                                                             \
    }                                                                        \
    float tm = fmaxf(                                                        \
        fmaxf(fmaxf(fmaxf(sv[0], sv[1]), fmaxf(sv[2], sv[3])),               \
              fmaxf(fmaxf(sv[4], sv[5]), fmaxf(sv[6], sv[7]))),              \
        fmaxf(fmaxf(fmaxf(sv[8], sv[9]), fmaxf(sv[10], sv[11])),             \
              fmaxf(fmaxf(sv[12], sv[13]), fmaxf(sv[14], sv[15]))));         \
    tm = xmax32(tm);                                                         \
    if (!__all(tm <= mcur + 64.f)) {                                         \
      float mn = fmaxf(mcur, tm);                                            \
      float sc = FEXP2((mcur - mn) * EXP2C);                                 \
      mcur = mn;                                                             \
      lcur *= sc;                                                            \
      _Pragma("unroll") for (int mb = 0; mb < 2; ++mb)                       \
          _Pragma("unroll") for (int r = 0; r < 16; ++r) oacc[mb][r] *= sc;  \
    }                                                                        \
    const float hm = mcur * EXP2C;                                           \
    float pf[16];                                                            \
    _Pragma("unroll") for (int r = 0; r < 16; ++r)                           \
        pf[r] = FEXP2(__builtin_fmaf(sv[r], EXP2C, -hm));                    \
    float ps = (((pf[0] + pf[1]) + (pf[2] + pf[3])) +                        \
                ((pf[4] + pf[5]) + (pf[6] + pf[7]))) +                       \
               (((pf[8] + pf[9]) + (pf[10] + pf[11])) +                      \
                ((pf[12] + pf[13]) + (pf[14] + pf[15])));                    \
    ps = xsum32(ps);                                                         \
    lcur += ps;                                                              \
    unsigned o01 = pkbf(pf[0], pf[1]), o23 = pkbf(pf[2], pf[3]);             \
    unsigned o45 = pkbf(pf[4], pf[5]), o67 = pkbf(pf[6], pf[7]);             \
    unsigned o89 = pkbf(pf[8], pf[9]), o1011 = pkbf(pf[10], pf[11]);         \
    unsigned o1213 = pkbf(pf[12], pf[13]), o1415 = pkbf(pf[14], pf[15]);     \
    plswap(o01, o45); plswap(o23, o67);                                      \
    plswap(o89, o1213); plswap(o1011, o1415);                                \
    uint4 w0 = { o01, o23, o45, o67 };                                       \
    uint4 w1 = { o89, o1011, o1213, o1415 };                                 \
    bf16x8 pb0 = __builtin_bit_cast(bf16x8, w0);                             \
    bf16x8 pb1 = __builtin_bit_cast(bf16x8, w1);                             \
    __builtin_amdgcn_s_setprio(1);                                           \
    oacc[0] = __builtin_amdgcn_mfma_f32_32x32x16_bf16(vf[0], pb0, oacc[0], 0, 0, 0); \
    oacc[0] = __builtin_amdgcn_mfma_f32_32x32x16_bf16(vf[1], pb1, oacc[0], 0, 0, 0); \
    oacc[1] = __builtin_amdgcn_mfma_f32_32x32x16_bf16(vf[2], pb0, oacc[1], 0, 0, 0); \
    oacc[1] = __builtin_amdgcn_mfma_f32_32x32x16_bf16(vf[3], pb1, oacc[1], 0, 0, 0); \
    __builtin_amdgcn_s_setprio(0);                                           \
  }

__global__ __launch_bounds__(256, 3) void attn_kernel(
    const bf16_t* __restrict__ qkv,
    const bf16_t* __restrict__ kfs, const bf16_t* __restrict__ vfs,
    const bf16_t* __restrict__ kfc, const bf16_t* __restrict__ vfc,
    bf16_t* __restrict__ obuf) {
  __shared__ __align__(16) float sO[4][34][64];

  const int tid = threadIdx.x;
  const int w = tid >> 6, l = tid & 63;
  const int ql = l & 31;
  const bool uhi = l >= 32;
  const int kv4 = uhi ? 4 : 0;
  const int hi8 = uhi ? 8 : 0;

  const int bid = blockIdx.x;
  const bool is_self = bid < 2048;
  int qt, bh, nt;
  if (is_self) {
    qt = 31 - (bid >> 6);
    bh = bid & 63;
    nt = qt + 1;
  } else {
    int cb = bid - 2048;
    qt = cb >> 6;
    bh = cb & 63;
    nt = 8;
  }
  const int b = bh >> 4, h = bh & 15;
  const int hcol = h * 64;
  const int q0 = qt * 32;

  const bf16_t* kba; const bf16_t* vba; int ooff;
  if (is_self) {
    kba = kfs + (size_t)bh * 32 * 2048; vba = vfs + (size_t)bh * 32 * 2048; ooff = 0;
  } else {
    kba = kfc + (size_t)bh * 8 * 2048;  vba = vfc + (size_t)bh * 8 * 2048;  ooff = 1024;
  }

  const bf16_t* qrow = qkv + (size_t)(b * 1024 + q0 + ql) * 3072 + hcol + hi8;
  bf16x8 qf[4];
#pragma unroll
  for (int ks = 0; ks < 4; ++ks) qf[ks] = *(const bf16x8*)(qrow + ks * 16);

  float mcur = -1e30f, lcur = 0.f;
  f32x16 sa = {};
  f32x16 oacc[2] = {};
  bf16x8 kf[4], vfA[4], vfB[4];

  int t = w;
  if (t < nt) { LOADK(t); LOADV(vfA, t); QKT(); }
  while (t < nt) {
    {
      const int nxt = t + 4;
      if (nxt < nt) { LOADK(nxt); LOADV(vfB, nxt); }
      SMPV(vfA, t);
      if (nxt < nt) QKT();
      t = nxt;
    }
    if (t >= nt) break;
    {
      const int nxt = t + 4;
      if (nxt < nt) { LOADK(nxt); LOADV(vfA, nxt); }
      SMPV(vfB, t);
      if (nxt < nt) QKT();
      t = nxt;
    }
  }

#pragma unroll
  for (int mb = 0; mb < 2; ++mb)
#pragma unroll
    for (int r = 0; r < 16; ++r)
      sO[w][mb * 16 + r][l] = oacc[mb][r];
  if (!uhi) { sO[w][32][ql] = mcur; sO[w][33][ql] = lcur; }
  __syncthreads();

  float m0 = sO[0][32][ql], m1 = sO[1][32][ql], m2 = sO[2][32][ql], m3 = sO[3][32][ql];
  float MM = fmaxf(fmaxf(m0, m1), fmaxf(m2, m3));
  float s0 = FEXP2((m0 - MM) * EXP2C), s1 = FEXP2((m1 - MM) * EXP2C);
  float s2 = FEXP2((m2 - MM) * EXP2C), s3 = FEXP2((m3 - MM) * EXP2C);
  float LL = sO[0][33][ql] * s0 + sO[1][33][ql] * s1 +
             sO[2][33][ql] * s2 + sO[3][33][ql] * s3;
  const float rl = 1.0f / LL;
  float mg[8];
#pragma unroll
  for (int jj = 0; jj < 8; ++jj) {
    int j = w * 8 + jj;
    mg[jj] = (sO[0][j][l] * s0 + sO[1][j][l] * s1 +
              sO[2][j][l] * s2 + sO[3][j][l] * s3) * rl;
  }
  __syncthreads();
  char* swb = (char*)&sO[0][0][0];
#pragma unroll
  for (int jj = 0; jj < 8; jj += 2) {
    int j0 = w * 8 + jj;
    int mb = j0 >> 4, r = j0 & 15, r2 = r >> 1;
    int hdb = (r2 & 1) * 2 + 8 * (r2 >> 1) + kv4 + mb * 32;
    int off = (ql * 128 + hdb * 2) ^ ((ql & 7) << 4);
    *(unsigned*)(swb + off) = pkbf(mg[jj], mg[jj + 1]);
  }
  __syncthreads();
  {
    const int orow = b * 2048 + ooff + q0;
    int q = tid >> 3, ch = tid & 7;
    int off = (q * 128 + ch * 16) ^ ((q & 7) << 4);
    uint4 d = *(uint4*)(swb + off);
    *(uint4*)&obuf[(size_t)(orow + q) * 1024 + hcol + ch * 8] = d;
  }
}

// ---------------------------------------------------------------------------
extern "C" void kernel_launch(void* const* d_in, const int* in_sizes, int n_in,
                              void* d_out, int out_size, void* d_ws, size_t ws_size,
                              hipStream_t stream) {
  (void)in_sizes; (void)n_in; (void)out_size; (void)ws_size;
  const float* x   = (const float*)d_in[0];
  const float* pkg = (const float*)d_in[1];
  const float* Wc  = (const float*)d_in[2];
  const float* bc  = (const float*)d_in[3];
  const float* Wk  = (const float*)d_in[4];
  const float* bk  = (const float*)d_in[5];
  const float* Wp  = (const float*)d_in[6];
  const float* bp  = (const float*)d_in[7];
  float* out = (float*)d_out;

  char* ws = (char*)d_ws;
  const size_t MB = 1u << 20;
  bf16_t* xb   = (bf16_t*)(ws + 0 * MB);   // [4096][1024]   8 MB (dead after qkv GEMM)
  bf16_t* pkb  = (bf16_t*)(ws + 8 * MB);   // [1024][1024]   2 MB (dead after kkv GEMM)
  bf16_t* Wct  = (bf16_t*)(ws + 10 * MB);  // [3072][1024]   6 MB (dead after qkv GEMM)
  bf16_t* Wkt  = (bf16_t*)(ws + 16 * MB);  // [2048][1024]   4 MB
  bf16_t* Wpt  = (bf16_t*)(ws + 20 * MB);  // [1024][1024]   2 MB
  bf16_t* kkvb = (bf16_t*)(ws + 22 * MB);  // [1024][2048]   4 MB
  bf16_t* abuf = (bf16_t*)(ws + 26 * MB);  // [8192][1024]  16 MB  (ws total 42 MB)
  bf16_t* vfs  = (bf16_t*)(ws + 0 * MB);   // packed self V^T frags  8 MB (reuses xb)
  bf16_t* kfc  = (bf16_t*)(ws + 8 * MB);   // packed cross K frags   2 MB (reuses pkb)
  bf16_t* vfc  = (bf16_t*)(ws + 10 * MB);  // packed cross V^T frags 2 MB (reuses Wct)
  bf16_t* qkvb = (bf16_t*)d_out;                      // [4096][3072] 24 MB
  bf16_t* kfs  = (bf16_t*)((char*)d_out + 24 * MB);   // packed self K frags 8 MB

  // 1: convert inputs + transpose-convert weights (fused)
  prep_kernel<<<11264, 256, 0, stream>>>(x, xb, pkg, pkb, Wc, Wct, Wk, Wkt, Wp, Wpt);
  // 2: qkv + kkv GEMM (256x128 tiles, XCD-swizzled)
  gemm2_kernel<<<448, 512, 0, stream>>>(xb, Wct, bc, qkvb, pkb, Wkt, bk, kkvb);
  // 3: fragment packing (self 32 tiles + cross 8 tiles) x 64 bh
  pack2_kernel<<<dim3(40, 64), 256, 0, stream>>>(qkvb, kfs, vfs, kkvb, kfc, vfc);
  // 4: attention (both branches)
  attn_kernel<<<4096, 256, 0, stream>>>(qkvb, kfs, vfs, kfc, vfc, abuf);
  // 5: output projection (256 blocks = 1/CU)
  gemm_proj_kernel<<<256, 512, 0, stream>>>(abuf, Wpt, bp, out);
}